// Round 6
// baseline (433.533 us; speedup 1.0000x reference)
//
#include <hip/hip_runtime.h>
#include <hip/hip_bf16.h>

// ---------------------------------------------------------------------------
// MessagePassingModel: N=10000 atoms, E=160000 edges, NC=9 SH channels,
// F=32 features, NB=16 radial basis, NITER=3.
// R5 profile: edge 49us x3 (VALU 29%, HBM 14% -> latency-bound, 83% of loop
// trips are inactive-edge scans); atom ~40us hidden (LDS-pipe bound: 1152
// ds-ops/wave). R6: (1) active-edge compaction + geometry precompute (once),
// (2) atom GEMV via v_readlane broadcast (VALU pipe) + hoisted W reads
// (LDS ops 1152 -> 192/wave), (3) y zero-fill instead of copy.
// ---------------------------------------------------------------------------

#define NITER 3

// wcvt (fp32 converted weights) layout offsets, in floats
#define OFF_WB    0        // [NITER][3][16][32] = 4608
#define OFF_W1    4608     // [NITER][3][32][32] = 9216
#define OFF_B1    13824    // [NITER][32] = 96
#define OFF_W2    13920    // 9216
#define OFF_B2    23136    // 96
#define OFF_WT00  23232    // [32][4] = 128
#define OFF_WT11  23360    // 128
#define OFF_WMONO 23488    // [4][4] = 16
#define OFF_EB    23504    // 18
#define OFF_EMB   23522    // [18][32] = 576
#define WC_TOTAL  24098

__device__ __forceinline__ float b2f(const __hip_bfloat16 v) { return __bfloat162float(v); }

// Analytic real-Gaunt coefficients for l<=2:
#define KC0 0.28209479177387814f
#define KG1 0.21850968611841584f
#define KG2 0.12615662610100802f
#define KG3 0.18022375157287861f
#define KG4 0.09011187578643931f
#define KG5 0.15607834722743988f

// --- sniff input float dtype + reset active-edge counter --------------------
__global__ void sniff_kernel(const void* __restrict__ pos, int* __restrict__ flag,
                             int* __restrict__ cnt) {
    if (blockIdx.x == 0 && threadIdx.x == 0) {
        const __hip_bfloat16* p = (const __hip_bfloat16*)pos;
        int isf32 = 0;
        for (int k = 0; k < 64; k++) {
            float v = b2f(p[k]);
            if (!(fabsf(v) < 1.0e6f)) isf32 = 1;   // NaN also trips
        }
        *flag = isf32;
        *cnt  = 0;
    }
}

__device__ __forceinline__ float ldany(const void* p, int i, bool f32) {
    return f32 ? ((const float*)p)[i] : b2f(((const __hip_bfloat16*)p)[i]);
}

// --- convert positions + all weights to fp32 workspace ----------------------
__global__ void convert_kernel(const void* pos, const void* Wb, const void* W1,
        const void* b1, const void* W2, const void* b2, const void* Wt00,
        const void* Wt11, const void* Wmono, const void* eb, const void* emb,
        float* __restrict__ posf, float* __restrict__ wc, int N,
        const int* __restrict__ flag) {
    int i = blockIdx.x * blockDim.x + threadIdx.x;
    bool f32 = (*flag) != 0;
    int np = N * 3;
    if (i < np) { posf[i] = ldany(pos, i, f32); return; }
    int j = i - np;
    if (j >= WC_TOTAL) return;
    const void* src; int rel;
    if      (j < OFF_W1)    { src = Wb;    rel = j; }
    else if (j < OFF_B1)    { src = W1;    rel = j - OFF_W1; }
    else if (j < OFF_W2)    { src = b1;    rel = j - OFF_B1; }
    else if (j < OFF_B2)    { src = W2;    rel = j - OFF_W2; }
    else if (j < OFF_WT00)  { src = b2;    rel = j - OFF_B2; }
    else if (j < OFF_WT11)  { src = Wt00;  rel = j - OFF_WT00; }
    else if (j < OFF_WMONO) { src = Wt11;  rel = j - OFF_WT11; }
    else if (j < OFF_EB)    { src = Wmono; rel = j - OFF_WMONO; }
    else if (j < OFF_EMB)   { src = eb;    rel = j - OFF_EB; }
    else                    { src = emb;   rel = j - OFF_EMB; }
    wc[j] = ldany(src, rel, f32);
}

// --- x[:,0,:] = embed[an], rest 0 -------------------------------------------
__global__ void init_x_kernel(const int* __restrict__ an, const float* __restrict__ wc,
                              float* __restrict__ x, int N) {
    int idx = blockIdx.x * blockDim.x + threadIdx.x;
    if (idx >= N * 288) return;
    int n = idx / 288, rem = idx % 288;
    float val = 0.0f;
    if (rem < 32) val = wc[OFF_EMB + an[n] * 32 + rem];
    x[idx] = val;
}

// --- y = 0 ------------------------------------------------------------------
__global__ void zero_kernel(float4* __restrict__ b, int n) {
    int i = blockIdx.x * blockDim.x + threadIdx.x;
    int stride = gridDim.x * blockDim.x;
    float4 z = make_float4(0.f, 0.f, 0.f, 0.f);
    for (; i < n; i += stride) b[i] = z;
}

// --- geometry helper (shared by compact + inline paths) ---------------------
__device__ __forceinline__ bool edge_geom(float dx, float dy, float dz,
                                          float* sp, float* rad) {
    float r2 = dx*dx + dy*dy + dz*dz + 1e-12f;
    if (r2 >= 16.0f) return false;
    float r  = sqrtf(r2);
    float t2 = r2 * 0.0625f;
    float fc = __expf(-t2 / (1.0f - t2));
    float u = 1.0f / (1.0f + r);
    float v = 1.0f - u;
    const float BIN[16] = {1.f,15.f,105.f,455.f,1365.f,3003.f,5005.f,6435.f,
                           6435.f,5005.f,3003.f,1365.f,455.f,105.f,15.f,1.f};
    float vp[16];
    vp[0] = 1.0f;
    #pragma unroll
    for (int k = 1; k < 16; k++) vp[k] = vp[k-1] * v;
    float up = 1.0f;
    #pragma unroll
    for (int n = 0; n < 16; n++) { rad[n] = BIN[n] * up * vp[15-n] * fc; up *= u; }
    float ir = 1.0f / r;
    float ux = dx*ir, uy = dy*ir, uz = dz*ir;
    const float c0 = 0.28209479177387814f, c1 = 0.4886025119029199f;
    const float c2a = 1.0925484305920792f, c2b = 0.31539156525252005f, c2c = 0.5462742152960396f;
    sp[0] = c0;
    sp[1] = c1*uy; sp[2] = c1*uz; sp[3] = c1*ux;
    sp[4] = c2a*ux*uy; sp[5] = c2a*uy*uz; sp[6] = c2b*(3.0f*uz*uz - 1.0f);
    sp[7] = c2a*ux*uz; sp[8] = c2c*(ux*ux - uy*uy);
    return true;
}

// --- compact: write {s,d,sph9,rad16} rows for active edges ------------------
__global__ void compact_kernel(const float* __restrict__ posf,
        const int* __restrict__ srcI, const int* __restrict__ dstI,
        float* __restrict__ geo, int* __restrict__ cnt, int E) {
    int e = blockIdx.x * blockDim.x + threadIdx.x;
    if (e >= E) return;
    int s = srcI[e], d = dstI[e];
    float sp[9], rad[16];
    if (!edge_geom(posf[s*3+0] - posf[d*3+0],
                   posf[s*3+1] - posf[d*3+1],
                   posf[s*3+2] - posf[d*3+2], sp, rad)) return;
    int p = atomicAdd(cnt, 1);
    float* gp = geo + (size_t)p * 32;
    gp[0] = __int_as_float(s);
    gp[1] = __int_as_float(d);
    #pragma unroll
    for (int a = 0; a < 9; a++) gp[2 + a] = sp[a];
    gp[11] = 0.0f;
    #pragma unroll
    for (int k = 0; k < 16; k++) gp[16 + k] = rad[k];
}

// --- shared message body (B0..B8 built, X gathered, 9 atomics) --------------
__device__ __forceinline__ void edge_message(const float* __restrict__ x,
        float* __restrict__ y, int s, int d, int f,
        float B0, float B1, float B2, float B3, float B4,
        float B5, float B6, float B7, float B8) {
    const float* xp = x + (size_t)s*288 + f;
    float X0 = xp[0],   X1 = xp[32],  X2 = xp[64],  X3 = xp[96],  X4 = xp[128];
    float X5 = xp[160], X6 = xp[192], X7 = xp[224], X8 = xp[256];
    float* yp = y + (size_t)d*288 + f;
    float m;
    m = KC0*(X0*B0 + X1*B1 + X2*B2 + X3*B3 + X4*B4 + X5*B5 + X6*B6 + X7*B7 + X8*B8);
    unsafeAtomicAdd(yp + 0, m);
    m = KC0*(X0*B1 + X1*B0) + KG1*(X3*B4 + X4*B3 + X2*B5 + X5*B2)
      - KG2*(X1*B6 + X6*B1) - KG1*(X1*B8 + X8*B1);
    unsafeAtomicAdd(yp + 32, m);
    m = KC0*(X0*B2 + X2*B0) + KG1*(X1*B5 + X5*B1 + X3*B7 + X7*B3)
      + 2.0f*KG2*(X2*B6 + X6*B2);
    unsafeAtomicAdd(yp + 64, m);
    m = KC0*(X0*B3 + X3*B0) + KG1*(X1*B4 + X4*B1 + X2*B7 + X7*B2)
      - KG2*(X3*B6 + X6*B3) + KG1*(X3*B8 + X8*B3);
    unsafeAtomicAdd(yp + 96, m);
    m = KC0*(X0*B4 + X4*B0) + KG1*(X1*B3 + X3*B1) + KG5*(X5*B7 + X7*B5)
      - KG3*(X4*B6 + X6*B4);
    unsafeAtomicAdd(yp + 128, m);
    m = KC0*(X0*B5 + X5*B0) + KG1*(X1*B2 + X2*B1) + KG5*(X4*B7 + X7*B4)
      + KG4*(X5*B6 + X6*B5) - KG5*(X5*B8 + X8*B5);
    unsafeAtomicAdd(yp + 160, m);
    m = KC0*(X0*B6 + X6*B0) - KG2*X1*B1 + 2.0f*KG2*X2*B2 - KG2*X3*B3
      - KG3*X4*B4 + KG4*X5*B5 + KG3*X6*B6 + KG4*X7*B7 - KG3*X8*B8;
    unsafeAtomicAdd(yp + 192, m);
    m = KC0*(X0*B7 + X7*B0) + KG1*(X2*B3 + X3*B2) + KG5*(X4*B5 + X5*B4)
      + KG4*(X6*B7 + X7*B6) + KG5*(X7*B8 + X8*B7);
    unsafeAtomicAdd(yp + 224, m);
    m = KC0*(X0*B8 + X8*B0) - KG1*X1*B1 + KG1*X3*B3 - KG5*X5*B5 + KG5*X7*B7
      - KG3*(X6*B8 + X8*B6);
    unsafeAtomicAdd(yp + 256, m);
}

// --- per-iteration edge kernel over COMPACTED active edges ------------------
__global__ __launch_bounds__(256) void edge_compact_kernel(
        const float* __restrict__ x, float* __restrict__ y,
        const float* __restrict__ geo, const int* __restrict__ cnt,
        const float* __restrict__ Wbi) {
    int f  = threadIdx.x & 31;
    int hw = (blockIdx.x * blockDim.x + threadIdx.x) >> 5;
    int nhw = gridDim.x * (blockDim.x >> 5);
    float w0[16], w1[16], w2[16];
    #pragma unroll
    for (int n = 0; n < 16; n++) {
        w0[n] = Wbi[(0*16 + n)*32 + f];
        w1[n] = Wbi[(1*16 + n)*32 + f];
        w2[n] = Wbi[(2*16 + n)*32 + f];
    }
    int nact = *cnt;
    for (int e = hw; e < nact; e += nhw) {
        const float4* gp = (const float4*)(geo + (size_t)e * 32);
        float4 h0 = gp[0], h1 = gp[1], h2 = gp[2];
        float4 r0 = gp[4], r1 = gp[5], r2 = gp[6], r3 = gp[7];
        int s = __float_as_int(h0.x), d = __float_as_int(h0.y);
        float rw0, rw1, rw2;
        {
            float rad[16] = {r0.x,r0.y,r0.z,r0.w, r1.x,r1.y,r1.z,r1.w,
                             r2.x,r2.y,r2.z,r2.w, r3.x,r3.y,r3.z,r3.w};
            rw0 = 0.f; rw1 = 0.f; rw2 = 0.f;
            #pragma unroll
            for (int n = 0; n < 16; n++) {
                rw0 = fmaf(rad[n], w0[n], rw0);
                rw1 = fmaf(rad[n], w1[n], rw1);
                rw2 = fmaf(rad[n], w2[n], rw2);
            }
        }
        float B0 = h0.z*rw0;
        float B1 = h0.w*rw1, B2 = h1.x*rw1, B3 = h1.y*rw1;
        float B4 = h1.z*rw2, B5 = h1.w*rw2, B6 = h2.x*rw2,
              B7 = h2.y*rw2, B8 = h2.z*rw2;
        edge_message(x, y, s, d, f, B0,B1,B2,B3,B4,B5,B6,B7,B8);
    }
}

// --- fallback: inline-geometry edge kernel (if ws too small for geo) --------
__global__ __launch_bounds__(256) void edge_inline_kernel(
        const float* __restrict__ x, float* __restrict__ y,
        const float* __restrict__ posf,
        const int* __restrict__ srcI, const int* __restrict__ dstI,
        const float* __restrict__ Wbi, int E) {
    int f  = threadIdx.x & 31;
    int hw = (blockIdx.x * blockDim.x + threadIdx.x) >> 5;
    int nhw = gridDim.x * (blockDim.x >> 5);
    float w0[16], w1[16], w2[16];
    #pragma unroll
    for (int n = 0; n < 16; n++) {
        w0[n] = Wbi[(0*16 + n)*32 + f];
        w1[n] = Wbi[(1*16 + n)*32 + f];
        w2[n] = Wbi[(2*16 + n)*32 + f];
    }
    for (int e = hw; e < E; e += nhw) {
        int s = srcI[e], d = dstI[e];
        float sp[9], rad[16];
        if (!edge_geom(posf[s*3+0] - posf[d*3+0],
                       posf[s*3+1] - posf[d*3+1],
                       posf[s*3+2] - posf[d*3+2], sp, rad)) continue;
        float rw0 = 0.f, rw1 = 0.f, rw2 = 0.f;
        #pragma unroll
        for (int n = 0; n < 16; n++) {
            rw0 = fmaf(rad[n], w0[n], rw0);
            rw1 = fmaf(rad[n], w1[n], rw1);
            rw2 = fmaf(rad[n], w2[n], rw2);
        }
        edge_message(x, y, s, d, f,
            sp[0]*rw0, sp[1]*rw1, sp[2]*rw1, sp[3]*rw1,
            sp[4]*rw2, sp[5]*rw2, sp[6]*rw2, sp[7]*rw2, sp[8]*rw2);
    }
}

// --- atom update: x += dense2(silu(dense1(x + ymsg))) -----------------------
// Wave64 = 2 atoms (lane&31 = output feature g). Input broadcasts via
// v_readlane (compile-time lane idx, VALU pipe) + cndmask to pick the
// half-wave's atom; W reads hoisted 3-per-fi (LDS ops 1152 -> 192/wave).
__global__ __launch_bounds__(256) void atom_kernel(
        float* __restrict__ x, const float* __restrict__ y,
        const float* __restrict__ W1i, const float* __restrict__ b1i,
        const float* __restrict__ W2i, const float* __restrict__ b2i, int N) {
    __shared__ float W1s[3*32*32];
    __shared__ float W2s[3*32*32];
    __shared__ float b1s[32], b2s[32];
    for (int idx = threadIdx.x; idx < 3072; idx += 256) {
        W1s[idx] = W1i[idx];
        W2s[idx] = W2i[idx];
    }
    if (threadIdx.x < 32) {
        b1s[threadIdx.x] = b1i[threadIdx.x];
        b2s[threadIdx.x] = b2i[threadIdx.x];
    }
    __syncthreads();
    int lane = threadIdx.x & 63;
    int g    = lane & 31;
    bool lo  = lane < 32;
    int wv   = blockIdx.x * 4 + (threadIdx.x >> 6);
    int n    = wv * 2 + (lane >> 5);          // lanes 0-31: atom A, 32-63: atom B
    bool act = n < N;
    const float* yb = y + (size_t)n * 288;
    const float* xb = x + (size_t)n * 288;
    float xv[9], yin[9];
    #pragma unroll
    for (int c = 0; c < 9; c++) {
        xv[c]  = act ? xb[c*32 + g] : 0.0f;
        yin[c] = act ? (xv[c] + yb[c*32 + g]) : 0.0f;
    }
    float acc[9];
    #pragma unroll
    for (int c = 0; c < 9; c++) acc[c] = (c == 0) ? b1s[g] : 0.0f;
    #pragma unroll
    for (int fi = 0; fi < 32; fi++) {
        float w0 = W1s[         fi*32 + g];
        float w1 = W1s[1024 +   fi*32 + g];
        float w2 = W1s[2048 +   fi*32 + g];
        #pragma unroll
        for (int c = 0; c < 9; c++) {
            float va = __int_as_float(__builtin_amdgcn_readlane(__float_as_int(yin[c]), fi));
            float vb = __int_as_float(__builtin_amdgcn_readlane(__float_as_int(yin[c]), fi + 32));
            float inv = lo ? va : vb;
            acc[c] = fmaf(inv, (c == 0) ? w0 : ((c < 4) ? w1 : w2), acc[c]);
        }
    }
    float sv[9];
    #pragma unroll
    for (int c = 0; c < 9; c++)
        sv[c] = acc[c] * __builtin_amdgcn_rcpf(1.0f + __expf(-acc[c]));   // silu
    #pragma unroll
    for (int c = 0; c < 9; c++) acc[c] = (c == 0) ? b2s[g] : 0.0f;
    #pragma unroll
    for (int fi = 0; fi < 32; fi++) {
        float w0 = W2s[         fi*32 + g];
        float w1 = W2s[1024 +   fi*32 + g];
        float w2 = W2s[2048 +   fi*32 + g];
        #pragma unroll
        for (int c = 0; c < 9; c++) {
            float va = __int_as_float(__builtin_amdgcn_readlane(__float_as_int(sv[c]), fi));
            float vb = __int_as_float(__builtin_amdgcn_readlane(__float_as_int(sv[c]), fi + 32));
            float inv = lo ? va : vb;
            acc[c] = fmaf(inv, (c == 0) ? w0 : ((c < 4) ? w1 : w2), acc[c]);
        }
    }
    if (act) {
        float* xw = x + (size_t)n * 288;
        #pragma unroll
        for (int c = 0; c < 9; c++) xw[c*32 + g] = xv[c] + acc[c];
    }
}

// --- readout (mono, dip) ----------------------------------------------------
__global__ void readout_kernel(const float* __restrict__ x,
        const int* __restrict__ an, const float* __restrict__ posf,
        const float* __restrict__ wc, void* __restrict__ out, int N,
        const int* __restrict__ flag) {
    int n = blockIdx.x * blockDim.x + threadIdx.x;
    if (n >= N) return;
    bool f32 = (*flag) != 0;
    const float* Wt00  = wc + OFF_WT00;
    const float* Wt11  = wc + OFF_WT11;
    const float* Wmono = wc + OFF_WMONO;
    const float* xb = x + (size_t)n * 288;
    float q[4] = {0.f, 0.f, 0.f, 0.f};
    for (int f = 0; f < 32; f++) {
        float xv = xb[f];
        #pragma unroll
        for (int j = 0; j < 4; j++) q[j] = fmaf(xv, Wt00[f*4 + j], q[j]);
    }
    float ebv = wc[OFF_EB + an[n]];
    #pragma unroll
    for (int m = 0; m < 4; m++) {
        float acc = ebv;
        #pragma unroll
        for (int j = 0; j < 4; j++) acc = fmaf(q[j], Wmono[j*4 + m], acc);
        if (f32) ((float*)out)[n*4 + m] = acc;
        else ((__hip_bfloat16*)out)[n*4 + m] = __float2bfloat16(acc);
    }
    #pragma unroll
    for (int c = 0; c < 3; c++) {
        float pc = posf[n*3 + c];
        const float* xc = xb + (1 + c)*32;
        float dq[4] = {0.f, 0.f, 0.f, 0.f};
        for (int f = 0; f < 32; f++) {
            float xv = xc[f];
            #pragma unroll
            for (int m = 0; m < 4; m++) dq[m] = fmaf(xv, Wt11[f*4 + m], dq[m]);
        }
        #pragma unroll
        for (int m = 0; m < 4; m++) {
            float v = dq[m];
            v = v * __builtin_amdgcn_rcpf(1.0f + __expf(-v));   // silu
            v = fminf(fmaxf(v, -0.3f), 0.3f);                   // clip
            v += pc;
            if (f32) ((float*)out)[N*4 + n*12 + c*4 + m] = v;
            else ((__hip_bfloat16*)out)[N*4 + n*12 + c*4 + m] = __float2bfloat16(v);
        }
    }
}

extern "C" void kernel_launch(void* const* d_in, const int* in_sizes, int n_in,
                              void* d_out, int out_size, void* d_ws, size_t ws_size,
                              hipStream_t stream) {
    const int* an    = (const int*)d_in[0];
    const void* pos  = d_in[1];
    const int* dstI  = (const int*)d_in[2];
    const int* srcI  = (const int*)d_in[3];
    const void* embed= d_in[4];
    const void* Wb   = d_in[5];
    const void* W1   = d_in[6];
    const void* b1   = d_in[7];
    const void* W2   = d_in[8];
    const void* b2   = d_in[9];
    const void* Wt00 = d_in[10];
    const void* Wt11 = d_in[11];
    const void* Wmono= d_in[12];
    const void* eb   = d_in[13];
    int N = in_sizes[0];
    int E = in_sizes[2];

    // ws layout: flag,cnt (16B) | x | y (N*288 f32 each) | posf (N*3) | wc | geo (E*32)
    int* flag   = (int*)d_ws;
    int* cnt    = flag + 1;
    float* x    = (float*)((char*)d_ws + 16);
    float* y    = x + (size_t)N * 288;
    float* posf = y + (size_t)N * 288;
    float* wc   = posf + (size_t)N * 3;
    float* geo  = wc + WC_TOTAL;
    size_t need_geo = 16 + ((size_t)N*288*2 + (size_t)N*3 + WC_TOTAL + (size_t)E*32) * 4;
    bool use_compact = (ws_size >= need_geo);

    sniff_kernel<<<1, 64, 0, stream>>>(pos, flag, cnt);
    {
        int tot = N * 3 + WC_TOTAL;
        convert_kernel<<<(tot + 255)/256, 256, 0, stream>>>(
            pos, Wb, W1, b1, W2, b2, Wt00, Wt11, Wmono, eb, embed,
            posf, wc, N, flag);
    }
    init_x_kernel<<<(N*288 + 255)/256, 256, 0, stream>>>(an, wc, x, N);
    if (use_compact)
        compact_kernel<<<(E + 255)/256, 256, 0, stream>>>(posf, srcI, dstI, geo, cnt, E);

    int ablocks = (N + 7) / 8;   // 8 atoms (4 waves x 2) per 256-thread block
    for (int i = 0; i < NITER; i++) {
        zero_kernel<<<512, 256, 0, stream>>>((float4*)y, N * 72);
        if (use_compact)
            edge_compact_kernel<<<2048, 256, 0, stream>>>(x, y, geo, cnt,
                wc + OFF_WB + (size_t)i*1536);
        else
            edge_inline_kernel<<<2048, 256, 0, stream>>>(x, y, posf, srcI, dstI,
                wc + OFF_WB + (size_t)i*1536, E);
        atom_kernel<<<ablocks, 256, 0, stream>>>(x, y,
            wc + OFF_W1 + (size_t)i*3072, wc + OFF_B1 + (size_t)i*32,
            wc + OFF_W2 + (size_t)i*3072, wc + OFF_B2 + (size_t)i*32, N);
    }
    readout_kernel<<<(N + 255)/256, 256, 0, stream>>>(x, an, posf, wc, d_out, N, flag);
}

// Round 7
// 382.614 us; speedup vs baseline: 1.1331x; 1.1331x over previous
//
#include <hip/hip_runtime.h>
#include <hip/hip_bf16.h>

// ---------------------------------------------------------------------------
// MessagePassingModel: N=10000 atoms, E=160000 edges, NC=9 SH channels,
// F=32 features, NB=16 radial basis, NITER=3.
// R6 post-mortem: readlane-GEMV atom kernel = 1152 VALU/atom (4x broadcast
// overhead) + ~40KB unrolled body (L1I thrash) -> 53us. R7: lane-owns-atom
// GEMV (zero broadcast redundancy, 2048 FMA/wave for 64 atoms), W via
// scalar loads (readfirstlane'd uniform index), memory routed through
// LDS tiles with pitch 33 (conflict-free). Atom kernel also zeroes y
// in-place (removes zero_kernel dispatches). Edge compaction kept from R6.
// ---------------------------------------------------------------------------

#define NITER 3

// wcvt (fp32 converted weights) layout offsets, in floats
#define OFF_WB    0        // [NITER][3][16][32] = 4608
#define OFF_W1    4608     // [NITER][3][32][32] = 9216
#define OFF_B1    13824    // [NITER][32] = 96
#define OFF_W2    13920    // 9216
#define OFF_B2    23136    // 96
#define OFF_WT00  23232    // [32][4] = 128
#define OFF_WT11  23360    // 128
#define OFF_WMONO 23488    // [4][4] = 16
#define OFF_EB    23504    // 18
#define OFF_EMB   23522    // [18][32] = 576
#define WC_TOTAL  24098

__device__ __forceinline__ float b2f(const __hip_bfloat16 v) { return __bfloat162float(v); }

// Analytic real-Gaunt coefficients for l<=2:
#define KC0 0.28209479177387814f
#define KG1 0.21850968611841584f
#define KG2 0.12615662610100802f
#define KG3 0.18022375157287861f
#define KG4 0.09011187578643931f
#define KG5 0.15607834722743988f

// --- sniff input float dtype + reset active-edge counter --------------------
__global__ void sniff_kernel(const void* __restrict__ pos, int* __restrict__ flag,
                             int* __restrict__ cnt) {
    if (blockIdx.x == 0 && threadIdx.x == 0) {
        const __hip_bfloat16* p = (const __hip_bfloat16*)pos;
        int isf32 = 0;
        for (int k = 0; k < 64; k++) {
            float v = b2f(p[k]);
            if (!(fabsf(v) < 1.0e6f)) isf32 = 1;   // NaN also trips
        }
        *flag = isf32;
        *cnt  = 0;
    }
}

__device__ __forceinline__ float ldany(const void* p, int i, bool f32) {
    return f32 ? ((const float*)p)[i] : b2f(((const __hip_bfloat16*)p)[i]);
}

// --- convert positions + all weights to fp32 workspace ----------------------
__global__ void convert_kernel(const void* pos, const void* Wb, const void* W1,
        const void* b1, const void* W2, const void* b2, const void* Wt00,
        const void* Wt11, const void* Wmono, const void* eb, const void* emb,
        float* __restrict__ posf, float* __restrict__ wc, int N,
        const int* __restrict__ flag) {
    int i = blockIdx.x * blockDim.x + threadIdx.x;
    bool f32 = (*flag) != 0;
    int np = N * 3;
    if (i < np) { posf[i] = ldany(pos, i, f32); return; }
    int j = i - np;
    if (j >= WC_TOTAL) return;
    const void* src; int rel;
    if      (j < OFF_W1)    { src = Wb;    rel = j; }
    else if (j < OFF_B1)    { src = W1;    rel = j - OFF_W1; }
    else if (j < OFF_W2)    { src = b1;    rel = j - OFF_B1; }
    else if (j < OFF_B2)    { src = W2;    rel = j - OFF_W2; }
    else if (j < OFF_WT00)  { src = b2;    rel = j - OFF_B2; }
    else if (j < OFF_WT11)  { src = Wt00;  rel = j - OFF_WT00; }
    else if (j < OFF_WMONO) { src = Wt11;  rel = j - OFF_WT11; }
    else if (j < OFF_EB)    { src = Wmono; rel = j - OFF_WMONO; }
    else if (j < OFF_EMB)   { src = eb;    rel = j - OFF_EB; }
    else                    { src = emb;   rel = j - OFF_EMB; }
    wc[j] = ldany(src, rel, f32);
}

// --- x[:,0,:] = embed[an], rest 0; y = 0 ------------------------------------
__global__ void init_xy_kernel(const int* __restrict__ an, const float* __restrict__ wc,
                               float* __restrict__ x, float* __restrict__ y, int N) {
    int idx = blockIdx.x * blockDim.x + threadIdx.x;
    if (idx >= N * 288) return;
    int n = idx / 288, rem = idx % 288;
    float val = 0.0f;
    if (rem < 32) val = wc[OFF_EMB + an[n] * 32 + rem];
    x[idx] = val;
    y[idx] = 0.0f;
}

// --- geometry helper (shared by compact + inline paths) ---------------------
__device__ __forceinline__ bool edge_geom(float dx, float dy, float dz,
                                          float* sp, float* rad) {
    float r2 = dx*dx + dy*dy + dz*dz + 1e-12f;
    if (r2 >= 16.0f) return false;
    float r  = sqrtf(r2);
    float t2 = r2 * 0.0625f;
    float fc = __expf(-t2 / (1.0f - t2));
    float u = 1.0f / (1.0f + r);
    float v = 1.0f - u;
    const float BIN[16] = {1.f,15.f,105.f,455.f,1365.f,3003.f,5005.f,6435.f,
                           6435.f,5005.f,3003.f,1365.f,455.f,105.f,15.f,1.f};
    float vp[16];
    vp[0] = 1.0f;
    #pragma unroll
    for (int k = 1; k < 16; k++) vp[k] = vp[k-1] * v;
    float up = 1.0f;
    #pragma unroll
    for (int n = 0; n < 16; n++) { rad[n] = BIN[n] * up * vp[15-n] * fc; up *= u; }
    float ir = 1.0f / r;
    float ux = dx*ir, uy = dy*ir, uz = dz*ir;
    const float c0 = 0.28209479177387814f, c1 = 0.4886025119029199f;
    const float c2a = 1.0925484305920792f, c2b = 0.31539156525252005f, c2c = 0.5462742152960396f;
    sp[0] = c0;
    sp[1] = c1*uy; sp[2] = c1*uz; sp[3] = c1*ux;
    sp[4] = c2a*ux*uy; sp[5] = c2a*uy*uz; sp[6] = c2b*(3.0f*uz*uz - 1.0f);
    sp[7] = c2a*ux*uz; sp[8] = c2c*(ux*ux - uy*uy);
    return true;
}

// --- compact: write {s,d,sph9,rad16} rows for active edges ------------------
__global__ void compact_kernel(const float* __restrict__ posf,
        const int* __restrict__ srcI, const int* __restrict__ dstI,
        float* __restrict__ geo, int* __restrict__ cnt, int E) {
    int e = blockIdx.x * blockDim.x + threadIdx.x;
    if (e >= E) return;
    int s = srcI[e], d = dstI[e];
    float sp[9], rad[16];
    if (!edge_geom(posf[s*3+0] - posf[d*3+0],
                   posf[s*3+1] - posf[d*3+1],
                   posf[s*3+2] - posf[d*3+2], sp, rad)) return;
    int p = atomicAdd(cnt, 1);
    float* gp = geo + (size_t)p * 32;
    gp[0] = __int_as_float(s);
    gp[1] = __int_as_float(d);
    #pragma unroll
    for (int a = 0; a < 9; a++) gp[2 + a] = sp[a];
    gp[11] = 0.0f;
    #pragma unroll
    for (int k = 0; k < 16; k++) gp[16 + k] = rad[k];
}

// --- shared message body (B0..B8 built, X gathered, 9 atomics) --------------
__device__ __forceinline__ void edge_message(const float* __restrict__ x,
        float* __restrict__ y, int s, int d, int f,
        float B0, float B1, float B2, float B3, float B4,
        float B5, float B6, float B7, float B8) {
    const float* xp = x + (size_t)s*288 + f;
    float X0 = xp[0],   X1 = xp[32],  X2 = xp[64],  X3 = xp[96],  X4 = xp[128];
    float X5 = xp[160], X6 = xp[192], X7 = xp[224], X8 = xp[256];
    float* yp = y + (size_t)d*288 + f;
    float m;
    m = KC0*(X0*B0 + X1*B1 + X2*B2 + X3*B3 + X4*B4 + X5*B5 + X6*B6 + X7*B7 + X8*B8);
    unsafeAtomicAdd(yp + 0, m);
    m = KC0*(X0*B1 + X1*B0) + KG1*(X3*B4 + X4*B3 + X2*B5 + X5*B2)
      - KG2*(X1*B6 + X6*B1) - KG1*(X1*B8 + X8*B1);
    unsafeAtomicAdd(yp + 32, m);
    m = KC0*(X0*B2 + X2*B0) + KG1*(X1*B5 + X5*B1 + X3*B7 + X7*B3)
      + 2.0f*KG2*(X2*B6 + X6*B2);
    unsafeAtomicAdd(yp + 64, m);
    m = KC0*(X0*B3 + X3*B0) + KG1*(X1*B4 + X4*B1 + X2*B7 + X7*B2)
      - KG2*(X3*B6 + X6*B3) + KG1*(X3*B8 + X8*B3);
    unsafeAtomicAdd(yp + 96, m);
    m = KC0*(X0*B4 + X4*B0) + KG1*(X1*B3 + X3*B1) + KG5*(X5*B7 + X7*B5)
      - KG3*(X4*B6 + X6*B4);
    unsafeAtomicAdd(yp + 128, m);
    m = KC0*(X0*B5 + X5*B0) + KG1*(X1*B2 + X2*B1) + KG5*(X4*B7 + X7*B4)
      + KG4*(X5*B6 + X6*B5) - KG5*(X5*B8 + X8*B5);
    unsafeAtomicAdd(yp + 160, m);
    m = KC0*(X0*B6 + X6*B0) - KG2*X1*B1 + 2.0f*KG2*X2*B2 - KG2*X3*B3
      - KG3*X4*B4 + KG4*X5*B5 + KG3*X6*B6 + KG4*X7*B7 - KG3*X8*B8;
    unsafeAtomicAdd(yp + 192, m);
    m = KC0*(X0*B7 + X7*B0) + KG1*(X2*B3 + X3*B2) + KG5*(X4*B5 + X5*B4)
      + KG4*(X6*B7 + X7*B6) + KG5*(X7*B8 + X8*B7);
    unsafeAtomicAdd(yp + 224, m);
    m = KC0*(X0*B8 + X8*B0) - KG1*X1*B1 + KG1*X3*B3 - KG5*X5*B5 + KG5*X7*B7
      - KG3*(X6*B8 + X8*B6);
    unsafeAtomicAdd(yp + 256, m);
}

// --- per-iteration edge kernel over COMPACTED active edges ------------------
__global__ __launch_bounds__(256) void edge_compact_kernel(
        const float* __restrict__ x, float* __restrict__ y,
        const float* __restrict__ geo, const int* __restrict__ cnt,
        const float* __restrict__ Wbi) {
    int f  = threadIdx.x & 31;
    int hw = (blockIdx.x * blockDim.x + threadIdx.x) >> 5;
    int nhw = gridDim.x * (blockDim.x >> 5);
    float w0[16], w1[16], w2[16];
    #pragma unroll
    for (int n = 0; n < 16; n++) {
        w0[n] = Wbi[(0*16 + n)*32 + f];
        w1[n] = Wbi[(1*16 + n)*32 + f];
        w2[n] = Wbi[(2*16 + n)*32 + f];
    }
    int nact = *cnt;
    for (int e = hw; e < nact; e += nhw) {
        const float4* gp = (const float4*)(geo + (size_t)e * 32);
        float4 h0 = gp[0], h1 = gp[1], h2 = gp[2];
        float4 r0 = gp[4], r1 = gp[5], r2 = gp[6], r3 = gp[7];
        int s = __float_as_int(h0.x), d = __float_as_int(h0.y);
        float rw0, rw1, rw2;
        {
            float rad[16] = {r0.x,r0.y,r0.z,r0.w, r1.x,r1.y,r1.z,r1.w,
                             r2.x,r2.y,r2.z,r2.w, r3.x,r3.y,r3.z,r3.w};
            rw0 = 0.f; rw1 = 0.f; rw2 = 0.f;
            #pragma unroll
            for (int n = 0; n < 16; n++) {
                rw0 = fmaf(rad[n], w0[n], rw0);
                rw1 = fmaf(rad[n], w1[n], rw1);
                rw2 = fmaf(rad[n], w2[n], rw2);
            }
        }
        float B0 = h0.z*rw0;
        float B1 = h0.w*rw1, B2 = h1.x*rw1, B3 = h1.y*rw1;
        float B4 = h1.z*rw2, B5 = h1.w*rw2, B6 = h2.x*rw2,
              B7 = h2.y*rw2, B8 = h2.z*rw2;
        edge_message(x, y, s, d, f, B0,B1,B2,B3,B4,B5,B6,B7,B8);
    }
}

// --- fallback: inline-geometry edge kernel (if ws too small for geo) --------
__global__ __launch_bounds__(256) void edge_inline_kernel(
        const float* __restrict__ x, float* __restrict__ y,
        const float* __restrict__ posf,
        const int* __restrict__ srcI, const int* __restrict__ dstI,
        const float* __restrict__ Wbi, int E) {
    int f  = threadIdx.x & 31;
    int hw = (blockIdx.x * blockDim.x + threadIdx.x) >> 5;
    int nhw = gridDim.x * (blockDim.x >> 5);
    float w0[16], w1[16], w2[16];
    #pragma unroll
    for (int n = 0; n < 16; n++) {
        w0[n] = Wbi[(0*16 + n)*32 + f];
        w1[n] = Wbi[(1*16 + n)*32 + f];
        w2[n] = Wbi[(2*16 + n)*32 + f];
    }
    for (int e = hw; e < E; e += nhw) {
        int s = srcI[e], d = dstI[e];
        float sp[9], rad[16];
        if (!edge_geom(posf[s*3+0] - posf[d*3+0],
                       posf[s*3+1] - posf[d*3+1],
                       posf[s*3+2] - posf[d*3+2], sp, rad)) continue;
        float rw0 = 0.f, rw1 = 0.f, rw2 = 0.f;
        #pragma unroll
        for (int n = 0; n < 16; n++) {
            rw0 = fmaf(rad[n], w0[n], rw0);
            rw1 = fmaf(rad[n], w1[n], rw1);
            rw2 = fmaf(rad[n], w2[n], rw2);
        }
        edge_message(x, y, s, d, f,
            sp[0]*rw0, sp[1]*rw1, sp[2]*rw1, sp[3]*rw1,
            sp[4]*rw2, sp[5]*rw2, sp[6]*rw2, sp[7]*rw2, sp[8]*rw2);
    }
}

// --- atom update: x += dense2(silu(dense1(x + ymsg))), and y := 0 -----------
// Work unit = (64-atom tile) x (1 channel), one wave each. Lane owns one atom:
// full 32-wide GEMV chain in registers, zero broadcast redundancy (2048
// useful FMA/wave). W is wave-uniform (readfirstlane'd unit id -> s_load).
// Global<->lane transpose via LDS tile with pitch 33 (33 = 1 mod 32 ->
// conflict-free row reads/writes). y is zeroed during staging.
__global__ __launch_bounds__(256) void atom_kernel(
        float* __restrict__ x, float* __restrict__ y,
        const float* __restrict__ W1i, const float* __restrict__ b1i,
        const float* __restrict__ W2i, const float* __restrict__ b2i,
        int N) {
    __shared__ float sm[4][64*33];
    int lane  = threadIdx.x & 63;
    int wslot = threadIdx.x >> 6;
    int u = __builtin_amdgcn_readfirstlane(blockIdx.x * 4 + wslot);
    int t = u / 9;
    int c = u - t * 9;                      // channel (uniform)
    int d = (c == 0) ? 0 : ((c < 4) ? 1 : 2);
    const float* W1 = W1i + d * 1024;
    const float* W2 = W2i + d * 1024;
    float* tile = sm[wslot];
    // ---- stage yin = x + y into LDS (coalesced); zero y in place ----
    #pragma unroll
    for (int k = 0; k < 8; k++) {
        int e  = lane * 4 + k * 256;        // 0..2047, f multiple of 4
        int al = e >> 5, f = e & 31;
        int ag = t * 64 + al;
        float4 s = make_float4(0.f, 0.f, 0.f, 0.f);
        if (ag < N) {
            float* yp = y + (size_t)ag * 288 + c * 32 + f;
            float4 xv = *(const float4*)(x + (size_t)ag * 288 + c * 32 + f);
            float4 yv = *(const float4*)yp;
            *(float4*)yp = make_float4(0.f, 0.f, 0.f, 0.f);
            s = make_float4(xv.x + yv.x, xv.y + yv.y, xv.z + yv.z, xv.w + yv.w);
        }
        *(float4*)(tile + al * 33 + f) = s;
    }
    __syncthreads();
    // ---- per-lane GEMV chain ----
    float yin[32];
    #pragma unroll
    for (int k = 0; k < 8; k++) {
        float4 v = *(const float4*)(tile + lane * 33 + 4 * k);
        yin[4*k+0] = v.x; yin[4*k+1] = v.y; yin[4*k+2] = v.z; yin[4*k+3] = v.w;
    }
    float acc[32];
    #pragma unroll
    for (int g = 0; g < 32; g++) acc[g] = (c == 0) ? b1i[g] : 0.0f;
    #pragma unroll
    for (int fi = 0; fi < 32; fi++) {
        float v = yin[fi];
        #pragma unroll
        for (int g = 0; g < 32; g++) acc[g] = fmaf(v, W1[fi*32 + g], acc[g]);
    }
    #pragma unroll
    for (int g = 0; g < 32; g++)
        acc[g] = acc[g] * __builtin_amdgcn_rcpf(1.0f + __expf(-acc[g]));  // silu
    float out[32];
    #pragma unroll
    for (int g = 0; g < 32; g++) out[g] = (c == 0) ? b2i[g] : 0.0f;
    #pragma unroll
    for (int fi = 0; fi < 32; fi++) {
        float v = acc[fi];
        #pragma unroll
        for (int g = 0; g < 32; g++) out[g] = fmaf(v, W2[fi*32 + g], out[g]);
    }
    // ---- own row back to LDS, then cooperative residual add + store ----
    #pragma unroll
    for (int k = 0; k < 8; k++)
        *(float4*)(tile + lane * 33 + 4 * k) =
            make_float4(out[4*k+0], out[4*k+1], out[4*k+2], out[4*k+3]);
    __syncthreads();
    #pragma unroll
    for (int k = 0; k < 8; k++) {
        int e  = lane * 4 + k * 256;
        int al = e >> 5, f = e & 31;
        int ag = t * 64 + al;
        if (ag < N) {
            float4 dv = *(const float4*)(tile + al * 33 + f);
            float* xp = x + (size_t)ag * 288 + c * 32 + f;
            float4 xv = *(const float4*)xp;
            *(float4*)xp = make_float4(xv.x + dv.x, xv.y + dv.y,
                                       xv.z + dv.z, xv.w + dv.w);
        }
    }
}

// --- readout (mono, dip) ----------------------------------------------------
__global__ void readout_kernel(const float* __restrict__ x,
        const int* __restrict__ an, const float* __restrict__ posf,
        const float* __restrict__ wc, void* __restrict__ out, int N,
        const int* __restrict__ flag) {
    int n = blockIdx.x * blockDim.x + threadIdx.x;
    if (n >= N) return;
    bool f32 = (*flag) != 0;
    const float* Wt00  = wc + OFF_WT00;
    const float* Wt11  = wc + OFF_WT11;
    const float* Wmono = wc + OFF_WMONO;
    const float* xb = x + (size_t)n * 288;
    float q[4] = {0.f, 0.f, 0.f, 0.f};
    for (int f = 0; f < 32; f++) {
        float xv = xb[f];
        #pragma unroll
        for (int j = 0; j < 4; j++) q[j] = fmaf(xv, Wt00[f*4 + j], q[j]);
    }
    float ebv = wc[OFF_EB + an[n]];
    #pragma unroll
    for (int m = 0; m < 4; m++) {
        float acc = ebv;
        #pragma unroll
        for (int j = 0; j < 4; j++) acc = fmaf(q[j], Wmono[j*4 + m], acc);
        if (f32) ((float*)out)[n*4 + m] = acc;
        else ((__hip_bfloat16*)out)[n*4 + m] = __float2bfloat16(acc);
    }
    #pragma unroll
    for (int c = 0; c < 3; c++) {
        float pc = posf[n*3 + c];
        const float* xc = xb + (1 + c)*32;
        float dq[4] = {0.f, 0.f, 0.f, 0.f};
        for (int f = 0; f < 32; f++) {
            float xv = xc[f];
            #pragma unroll
            for (int m = 0; m < 4; m++) dq[m] = fmaf(xv, Wt11[f*4 + m], dq[m]);
        }
        #pragma unroll
        for (int m = 0; m < 4; m++) {
            float v = dq[m];
            v = v * __builtin_amdgcn_rcpf(1.0f + __expf(-v));   // silu
            v = fminf(fmaxf(v, -0.3f), 0.3f);                   // clip
            v += pc;
            if (f32) ((float*)out)[N*4 + n*12 + c*4 + m] = v;
            else ((__hip_bfloat16*)out)[N*4 + n*12 + c*4 + m] = __float2bfloat16(v);
        }
    }
}

extern "C" void kernel_launch(void* const* d_in, const int* in_sizes, int n_in,
                              void* d_out, int out_size, void* d_ws, size_t ws_size,
                              hipStream_t stream) {
    const int* an    = (const int*)d_in[0];
    const void* pos  = d_in[1];
    const int* dstI  = (const int*)d_in[2];
    const int* srcI  = (const int*)d_in[3];
    const void* embed= d_in[4];
    const void* Wb   = d_in[5];
    const void* W1   = d_in[6];
    const void* b1   = d_in[7];
    const void* W2   = d_in[8];
    const void* b2   = d_in[9];
    const void* Wt00 = d_in[10];
    const void* Wt11 = d_in[11];
    const void* Wmono= d_in[12];
    const void* eb   = d_in[13];
    int N = in_sizes[0];
    int E = in_sizes[2];

    // ws layout: flag,cnt (16B) | x | y (N*288 f32 each) | posf (N*3) | wc | geo (E*32)
    int* flag   = (int*)d_ws;
    int* cnt    = flag + 1;
    float* x    = (float*)((char*)d_ws + 16);
    float* y    = x + (size_t)N * 288;
    float* posf = y + (size_t)N * 288;
    float* wc   = posf + (size_t)N * 3;
    float* geo  = wc + WC_TOTAL;
    size_t need_geo = 16 + ((size_t)N*288*2 + (size_t)N*3 + WC_TOTAL + (size_t)E*32) * 4;
    bool use_compact = (ws_size >= need_geo);

    sniff_kernel<<<1, 64, 0, stream>>>(pos, flag, cnt);
    {
        int tot = N * 3 + WC_TOTAL;
        convert_kernel<<<(tot + 255)/256, 256, 0, stream>>>(
            pos, Wb, W1, b1, W2, b2, Wt00, Wt11, Wmono, eb, embed,
            posf, wc, N, flag);
    }
    init_xy_kernel<<<(N*288 + 255)/256, 256, 0, stream>>>(an, wc, x, y, N);
    if (use_compact)
        compact_kernel<<<(E + 255)/256, 256, 0, stream>>>(posf, srcI, dstI, geo, cnt, E);

    int ntiles  = (N + 63) / 64;
    int nunits  = ntiles * 9;
    int ablocks = (nunits + 3) / 4;
    for (int i = 0; i < NITER; i++) {
        if (use_compact)
            edge_compact_kernel<<<2048, 256, 0, stream>>>(x, y, geo, cnt,
                wc + OFF_WB + (size_t)i*1536);
        else
            edge_inline_kernel<<<2048, 256, 0, stream>>>(x, y, posf, srcI, dstI,
                wc + OFF_WB + (size_t)i*1536, E);
        atom_kernel<<<ablocks, 256, 0, stream>>>(x, y,
            wc + OFF_W1 + (size_t)i*3072, wc + OFF_B1 + (size_t)i*32,
            wc + OFF_W2 + (size_t)i*3072, wc + OFF_B2 + (size_t)i*32, N);
    }
    readout_kernel<<<(N + 255)/256, 256, 0, stream>>>(x, an, posf, wc, d_out, N, flag);
}

// Round 8
// 352.014 us; speedup vs baseline: 1.2316x; 1.0869x over previous
//
#include <hip/hip_runtime.h>
#include <hip/hip_bf16.h>

// ---------------------------------------------------------------------------
// MessagePassingModel: N=10000 atoms, E=160000 edges, NC=9 SH channels,
// F=32 features, NB=16 radial basis, NITER=3.
// R7 profile: edge_compact 43us x3, VALU 8.8%, HBM 16%, WRITE 38.9MB ->
// bound by atomic-RMW scatter through L2. R8: CSR dst-gather edge kernel
// (zero atomics in the hot loop): compact -> per-dst histogram -> 1-block
// scan -> scatter geo into CSR order (all once per launch); per-iteration
// kernel gathers per-dst edges, accumulates 9 channels in registers, plain
// coalesced stores. Atom kernel (R7 lane-owns-atom GEMV) unchanged; its
// y-zeroing only enabled in the no-CSR fallback path.
// ---------------------------------------------------------------------------

#define NITER 3

// wcvt (fp32 converted weights) layout offsets, in floats
#define OFF_WB    0        // [NITER][3][16][32] = 4608
#define OFF_W1    4608     // [NITER][3][32][32] = 9216
#define OFF_B1    13824    // [NITER][32] = 96
#define OFF_W2    13920    // 9216
#define OFF_B2    23136    // 96
#define OFF_WT00  23232    // [32][4] = 128
#define OFF_WT11  23360    // 128
#define OFF_WMONO 23488    // [4][4] = 16
#define OFF_EB    23504    // 18
#define OFF_EMB   23522    // [18][32] = 576
#define WC_TOTAL  24098

__device__ __forceinline__ float b2f(const __hip_bfloat16 v) { return __bfloat162float(v); }

// Analytic real-Gaunt coefficients for l<=2:
#define KC0 0.28209479177387814f
#define KG1 0.21850968611841584f
#define KG2 0.12615662610100802f
#define KG3 0.18022375157287861f
#define KG4 0.09011187578643931f
#define KG5 0.15607834722743988f

// --- sniff input float dtype + reset active-edge counter --------------------
__global__ void sniff_kernel(const void* __restrict__ pos, int* __restrict__ flag,
                             int* __restrict__ cnt) {
    if (blockIdx.x == 0 && threadIdx.x == 0) {
        const __hip_bfloat16* p = (const __hip_bfloat16*)pos;
        int isf32 = 0;
        for (int k = 0; k < 64; k++) {
            float v = b2f(p[k]);
            if (!(fabsf(v) < 1.0e6f)) isf32 = 1;   // NaN also trips
        }
        *flag = isf32;
        *cnt  = 0;
    }
}

__device__ __forceinline__ float ldany(const void* p, int i, bool f32) {
    return f32 ? ((const float*)p)[i] : b2f(((const __hip_bfloat16*)p)[i]);
}

// --- convert positions + weights to fp32 ws; zero per-dst degree array ------
__global__ void convert_kernel(const void* pos, const void* Wb, const void* W1,
        const void* b1, const void* W2, const void* b2, const void* Wt00,
        const void* Wt11, const void* Wmono, const void* eb, const void* emb,
        float* __restrict__ posf, float* __restrict__ wc, int* __restrict__ deg,
        int N, const int* __restrict__ flag) {
    int i = blockIdx.x * blockDim.x + threadIdx.x;
    bool f32 = (*flag) != 0;
    int np = N * 3;
    if (i < np) { posf[i] = ldany(pos, i, f32); return; }
    int j = i - np;
    if (j >= WC_TOTAL) {
        int k = j - WC_TOTAL;
        if (k < N) deg[k] = 0;
        return;
    }
    const void* src; int rel;
    if      (j < OFF_W1)    { src = Wb;    rel = j; }
    else if (j < OFF_B1)    { src = W1;    rel = j - OFF_W1; }
    else if (j < OFF_W2)    { src = b1;    rel = j - OFF_B1; }
    else if (j < OFF_B2)    { src = W2;    rel = j - OFF_W2; }
    else if (j < OFF_WT00)  { src = b2;    rel = j - OFF_B2; }
    else if (j < OFF_WT11)  { src = Wt00;  rel = j - OFF_WT00; }
    else if (j < OFF_WMONO) { src = Wt11;  rel = j - OFF_WT11; }
    else if (j < OFF_EB)    { src = Wmono; rel = j - OFF_WMONO; }
    else if (j < OFF_EMB)   { src = eb;    rel = j - OFF_EB; }
    else                    { src = emb;   rel = j - OFF_EMB; }
    wc[j] = ldany(src, rel, f32);
}

// --- x[:,0,:] = embed[an], rest 0; y = 0 ------------------------------------
__global__ void init_xy_kernel(const int* __restrict__ an, const float* __restrict__ wc,
                               float* __restrict__ x, float* __restrict__ y, int N) {
    int idx = blockIdx.x * blockDim.x + threadIdx.x;
    if (idx >= N * 288) return;
    int n = idx / 288, rem = idx % 288;
    float val = 0.0f;
    if (rem < 32) val = wc[OFF_EMB + an[n] * 32 + rem];
    x[idx] = val;
    y[idx] = 0.0f;
}

// --- geometry helper --------------------------------------------------------
__device__ __forceinline__ bool edge_geom(float dx, float dy, float dz,
                                          float* sp, float* rad) {
    float r2 = dx*dx + dy*dy + dz*dz + 1e-12f;
    if (r2 >= 16.0f) return false;
    float r  = sqrtf(r2);
    float t2 = r2 * 0.0625f;
    float fc = __expf(-t2 / (1.0f - t2));
    float u = 1.0f / (1.0f + r);
    float v = 1.0f - u;
    const float BIN[16] = {1.f,15.f,105.f,455.f,1365.f,3003.f,5005.f,6435.f,
                           6435.f,5005.f,3003.f,1365.f,455.f,105.f,15.f,1.f};
    float vp[16];
    vp[0] = 1.0f;
    #pragma unroll
    for (int k = 1; k < 16; k++) vp[k] = vp[k-1] * v;
    float up = 1.0f;
    #pragma unroll
    for (int n = 0; n < 16; n++) { rad[n] = BIN[n] * up * vp[15-n] * fc; up *= u; }
    float ir = 1.0f / r;
    float ux = dx*ir, uy = dy*ir, uz = dz*ir;
    const float c0 = 0.28209479177387814f, c1 = 0.4886025119029199f;
    const float c2a = 1.0925484305920792f, c2b = 0.31539156525252005f, c2c = 0.5462742152960396f;
    sp[0] = c0;
    sp[1] = c1*uy; sp[2] = c1*uz; sp[3] = c1*ux;
    sp[4] = c2a*ux*uy; sp[5] = c2a*uy*uz; sp[6] = c2b*(3.0f*uz*uz - 1.0f);
    sp[7] = c2a*ux*uz; sp[8] = c2c*(ux*ux - uy*uy);
    return true;
}

// --- compact: geo rows for active edges + per-dst histogram -----------------
__global__ void compact_kernel(const float* __restrict__ posf,
        const int* __restrict__ srcI, const int* __restrict__ dstI,
        float* __restrict__ geo, int* __restrict__ cnt, int* __restrict__ deg,
        int E) {
    int e = blockIdx.x * blockDim.x + threadIdx.x;
    if (e >= E) return;
    int s = srcI[e], d = dstI[e];
    float sp[9], rad[16];
    if (!edge_geom(posf[s*3+0] - posf[d*3+0],
                   posf[s*3+1] - posf[d*3+1],
                   posf[s*3+2] - posf[d*3+2], sp, rad)) return;
    int p = atomicAdd(cnt, 1);
    atomicAdd(&deg[d], 1);
    float* gp = geo + (size_t)p * 32;
    gp[0] = __int_as_float(s);
    gp[1] = __int_as_float(d);
    #pragma unroll
    for (int a = 0; a < 9; a++) gp[2 + a] = sp[a];
    gp[11] = 0.0f;
    #pragma unroll
    for (int k = 0; k < 16; k++) gp[16 + k] = rad[k];
}

// --- single-block exclusive scan of deg -> rowstart, cursor -----------------
__global__ __launch_bounds__(1024) void scan_kernel(const int* __restrict__ deg,
        int* __restrict__ rowstart, int* __restrict__ cursor, int N) {
    __shared__ int part[1024];
    int tid = threadIdx.x;
    int chunk = (N + 1023) / 1024;
    int beg = tid * chunk;
    int sum = 0;
    for (int k = 0; k < chunk; k++) {
        int i = beg + k;
        if (i < N) sum += deg[i];
    }
    part[tid] = sum;
    __syncthreads();
    for (int off = 1; off < 1024; off <<= 1) {
        int v = (tid >= off) ? part[tid - off] : 0;
        __syncthreads();
        part[tid] += v;
        __syncthreads();
    }
    int run = (tid == 0) ? 0 : part[tid - 1];
    for (int k = 0; k < chunk; k++) {
        int i = beg + k;
        if (i < N) { rowstart[i] = run; cursor[i] = run; run += deg[i]; }
    }
    if (tid == 1023) rowstart[N] = run;
}

// --- scatter geo rows into CSR order ----------------------------------------
__global__ void scatter_kernel(const float* __restrict__ geo,
        float* __restrict__ geo2, int* __restrict__ cursor,
        const int* __restrict__ cnt, int E) {
    int e = blockIdx.x * blockDim.x + threadIdx.x;
    if (e >= *cnt) return;
    const float4* src = (const float4*)(geo + (size_t)e * 32);
    int d = __float_as_int(geo[(size_t)e * 32 + 1]);
    int slot = atomicAdd(&cursor[d], 1);
    float4* dst = (float4*)(geo2 + (size_t)slot * 32);
    #pragma unroll
    for (int k = 0; k < 8; k++) dst[k] = src[k];
}

// --- per-iteration: dst-gather message accumulation (NO atomics) ------------
// Half-wave of 32 lanes (= F) per dst atom; loops its CSR edge list,
// accumulates all 9 channels in registers, 9 coalesced 128B stores.
__global__ __launch_bounds__(256) void edge_gather_kernel(
        const float* __restrict__ x, float* __restrict__ y,
        const float* __restrict__ geo2, const int* __restrict__ rowstart,
        const float* __restrict__ Wbi, int N) {
    int f = threadIdx.x & 31;
    int n = (blockIdx.x * blockDim.x + threadIdx.x) >> 5;   // dst atom
    if (n >= N) return;
    float w0[16], w1[16], w2[16];
    #pragma unroll
    for (int k = 0; k < 16; k++) {
        w0[k] = Wbi[(0*16 + k)*32 + f];
        w1[k] = Wbi[(1*16 + k)*32 + f];
        w2[k] = Wbi[(2*16 + k)*32 + f];
    }
    float A0=0.f,A1=0.f,A2=0.f,A3=0.f,A4=0.f,A5=0.f,A6=0.f,A7=0.f,A8=0.f;
    int beg = rowstart[n], end = rowstart[n+1];
    for (int e = beg; e < end; e++) {
        const float4* gp = (const float4*)(geo2 + (size_t)e * 32);
        float4 h0 = gp[0], h1 = gp[1], h2 = gp[2];
        float4 r0 = gp[4], r1 = gp[5], r2 = gp[6], r3 = gp[7];
        int s = __float_as_int(h0.x);
        float rad[16] = {r0.x,r0.y,r0.z,r0.w, r1.x,r1.y,r1.z,r1.w,
                         r2.x,r2.y,r2.z,r2.w, r3.x,r3.y,r3.z,r3.w};
        float rw0 = 0.f, rw1 = 0.f, rw2 = 0.f;
        #pragma unroll
        for (int k = 0; k < 16; k++) {
            rw0 = fmaf(rad[k], w0[k], rw0);
            rw1 = fmaf(rad[k], w1[k], rw1);
            rw2 = fmaf(rad[k], w2[k], rw2);
        }
        float B0 = h0.z*rw0;
        float B1 = h0.w*rw1, B2 = h1.x*rw1, B3 = h1.y*rw1;
        float B4 = h1.z*rw2, B5 = h1.w*rw2, B6 = h2.x*rw2,
              B7 = h2.y*rw2, B8 = h2.z*rw2;
        const float* xp = x + (size_t)s*288 + f;
        float X0 = xp[0],   X1 = xp[32],  X2 = xp[64],  X3 = xp[96],  X4 = xp[128];
        float X5 = xp[160], X6 = xp[192], X7 = xp[224], X8 = xp[256];
        A0 += KC0*(X0*B0 + X1*B1 + X2*B2 + X3*B3 + X4*B4 + X5*B5 + X6*B6 + X7*B7 + X8*B8);
        A1 += KC0*(X0*B1 + X1*B0) + KG1*(X3*B4 + X4*B3 + X2*B5 + X5*B2)
            - KG2*(X1*B6 + X6*B1) - KG1*(X1*B8 + X8*B1);
        A2 += KC0*(X0*B2 + X2*B0) + KG1*(X1*B5 + X5*B1 + X3*B7 + X7*B3)
            + 2.0f*KG2*(X2*B6 + X6*B2);
        A3 += KC0*(X0*B3 + X3*B0) + KG1*(X1*B4 + X4*B1 + X2*B7 + X7*B2)
            - KG2*(X3*B6 + X6*B3) + KG1*(X3*B8 + X8*B3);
        A4 += KC0*(X0*B4 + X4*B0) + KG1*(X1*B3 + X3*B1) + KG5*(X5*B7 + X7*B5)
            - KG3*(X4*B6 + X6*B4);
        A5 += KC0*(X0*B5 + X5*B0) + KG1*(X1*B2 + X2*B1) + KG5*(X4*B7 + X7*B4)
            + KG4*(X5*B6 + X6*B5) - KG5*(X5*B8 + X8*B5);
        A6 += KC0*(X0*B6 + X6*B0) - KG2*X1*B1 + 2.0f*KG2*X2*B2 - KG2*X3*B3
            - KG3*X4*B4 + KG4*X5*B5 + KG3*X6*B6 + KG4*X7*B7 - KG3*X8*B8;
        A7 += KC0*(X0*B7 + X7*B0) + KG1*(X2*B3 + X3*B2) + KG5*(X4*B5 + X5*B4)
            + KG4*(X6*B7 + X7*B6) + KG5*(X7*B8 + X8*B7);
        A8 += KC0*(X0*B8 + X8*B0) - KG1*X1*B1 + KG1*X3*B3 - KG5*X5*B5 + KG5*X7*B7
            - KG3*(X6*B8 + X8*B6);
    }
    float* yp = y + (size_t)n * 288 + f;
    yp[0]   = A0; yp[32]  = A1; yp[64]  = A2; yp[96]  = A3; yp[128] = A4;
    yp[160] = A5; yp[192] = A6; yp[224] = A7; yp[256] = A8;
}

// --- fallback: inline-geometry edge kernel with atomics ---------------------
__device__ __forceinline__ void edge_message(const float* __restrict__ x,
        float* __restrict__ y, int s, int d, int f,
        float B0, float B1, float B2, float B3, float B4,
        float B5, float B6, float B7, float B8) {
    const float* xp = x + (size_t)s*288 + f;
    float X0 = xp[0],   X1 = xp[32],  X2 = xp[64],  X3 = xp[96],  X4 = xp[128];
    float X5 = xp[160], X6 = xp[192], X7 = xp[224], X8 = xp[256];
    float* yp = y + (size_t)d*288 + f;
    float m;
    m = KC0*(X0*B0 + X1*B1 + X2*B2 + X3*B3 + X4*B4 + X5*B5 + X6*B6 + X7*B7 + X8*B8);
    unsafeAtomicAdd(yp + 0, m);
    m = KC0*(X0*B1 + X1*B0) + KG1*(X3*B4 + X4*B3 + X2*B5 + X5*B2)
      - KG2*(X1*B6 + X6*B1) - KG1*(X1*B8 + X8*B1);
    unsafeAtomicAdd(yp + 32, m);
    m = KC0*(X0*B2 + X2*B0) + KG1*(X1*B5 + X5*B1 + X3*B7 + X7*B3)
      + 2.0f*KG2*(X2*B6 + X6*B2);
    unsafeAtomicAdd(yp + 64, m);
    m = KC0*(X0*B3 + X3*B0) + KG1*(X1*B4 + X4*B1 + X2*B7 + X7*B2)
      - KG2*(X3*B6 + X6*B3) + KG1*(X3*B8 + X8*B3);
    unsafeAtomicAdd(yp + 96, m);
    m = KC0*(X0*B4 + X4*B0) + KG1*(X1*B3 + X3*B1) + KG5*(X5*B7 + X7*B5)
      - KG3*(X4*B6 + X6*B4);
    unsafeAtomicAdd(yp + 128, m);
    m = KC0*(X0*B5 + X5*B0) + KG1*(X1*B2 + X2*B1) + KG5*(X4*B7 + X7*B4)
      + KG4*(X5*B6 + X6*B5) - KG5*(X5*B8 + X8*B5);
    unsafeAtomicAdd(yp + 160, m);
    m = KC0*(X0*B6 + X6*B0) - KG2*X1*B1 + 2.0f*KG2*X2*B2 - KG2*X3*B3
      - KG3*X4*B4 + KG4*X5*B5 + KG3*X6*B6 + KG4*X7*B7 - KG3*X8*B8;
    unsafeAtomicAdd(yp + 192, m);
    m = KC0*(X0*B7 + X7*B0) + KG1*(X2*B3 + X3*B2) + KG5*(X4*B5 + X5*B4)
      + KG4*(X6*B7 + X7*B6) + KG5*(X7*B8 + X8*B7);
    unsafeAtomicAdd(yp + 224, m);
    m = KC0*(X0*B8 + X8*B0) - KG1*X1*B1 + KG1*X3*B3 - KG5*X5*B5 + KG5*X7*B7
      - KG3*(X6*B8 + X8*B6);
    unsafeAtomicAdd(yp + 256, m);
}

__global__ __launch_bounds__(256) void edge_inline_kernel(
        const float* __restrict__ x, float* __restrict__ y,
        const float* __restrict__ posf,
        const int* __restrict__ srcI, const int* __restrict__ dstI,
        const float* __restrict__ Wbi, int E) {
    int f  = threadIdx.x & 31;
    int hw = (blockIdx.x * blockDim.x + threadIdx.x) >> 5;
    int nhw = gridDim.x * (blockDim.x >> 5);
    float w0[16], w1[16], w2[16];
    #pragma unroll
    for (int n = 0; n < 16; n++) {
        w0[n] = Wbi[(0*16 + n)*32 + f];
        w1[n] = Wbi[(1*16 + n)*32 + f];
        w2[n] = Wbi[(2*16 + n)*32 + f];
    }
    for (int e = hw; e < E; e += nhw) {
        int s = srcI[e], d = dstI[e];
        float sp[9], rad[16];
        if (!edge_geom(posf[s*3+0] - posf[d*3+0],
                       posf[s*3+1] - posf[d*3+1],
                       posf[s*3+2] - posf[d*3+2], sp, rad)) continue;
        float rw0 = 0.f, rw1 = 0.f, rw2 = 0.f;
        #pragma unroll
        for (int n = 0; n < 16; n++) {
            rw0 = fmaf(rad[n], w0[n], rw0);
            rw1 = fmaf(rad[n], w1[n], rw1);
            rw2 = fmaf(rad[n], w2[n], rw2);
        }
        edge_message(x, y, s, d, f,
            sp[0]*rw0, sp[1]*rw1, sp[2]*rw1, sp[3]*rw1,
            sp[4]*rw2, sp[5]*rw2, sp[6]*rw2, sp[7]*rw2, sp[8]*rw2);
    }
}

// --- atom update: x += dense2(silu(dense1(x + ymsg))) -----------------------
// R7 lane-owns-atom GEMV via LDS pitch-33 transpose. zero_y only for the
// atomic fallback path (CSR gather fully rewrites y each iteration).
__global__ __launch_bounds__(256) void atom_kernel(
        float* __restrict__ x, float* __restrict__ y,
        const float* __restrict__ W1i, const float* __restrict__ b1i,
        const float* __restrict__ W2i, const float* __restrict__ b2i,
        int N, int zero_y) {
    __shared__ float sm[4][64*33];
    int lane  = threadIdx.x & 63;
    int wslot = threadIdx.x >> 6;
    int u = __builtin_amdgcn_readfirstlane(blockIdx.x * 4 + wslot);
    int t = u / 9;
    int c = u - t * 9;                      // channel (uniform)
    int d = (c == 0) ? 0 : ((c < 4) ? 1 : 2);
    const float* W1 = W1i + d * 1024;
    const float* W2 = W2i + d * 1024;
    float* tile = sm[wslot];
    #pragma unroll
    for (int k = 0; k < 8; k++) {
        int e  = lane * 4 + k * 256;
        int al = e >> 5, f = e & 31;
        int ag = t * 64 + al;
        float4 s = make_float4(0.f, 0.f, 0.f, 0.f);
        if (ag < N) {
            float* yp = y + (size_t)ag * 288 + c * 32 + f;
            float4 xv = *(const float4*)(x + (size_t)ag * 288 + c * 32 + f);
            float4 yv = *(const float4*)yp;
            if (zero_y) *(float4*)yp = make_float4(0.f, 0.f, 0.f, 0.f);
            s = make_float4(xv.x + yv.x, xv.y + yv.y, xv.z + yv.z, xv.w + yv.w);
        }
        *(float4*)(tile + al * 33 + f) = s;
    }
    __syncthreads();
    float yin[32];
    #pragma unroll
    for (int k = 0; k < 8; k++) {
        float4 v = *(const float4*)(tile + lane * 33 + 4 * k);
        yin[4*k+0] = v.x; yin[4*k+1] = v.y; yin[4*k+2] = v.z; yin[4*k+3] = v.w;
    }
    float acc[32];
    #pragma unroll
    for (int g = 0; g < 32; g++) acc[g] = (c == 0) ? b1i[g] : 0.0f;
    #pragma unroll
    for (int fi = 0; fi < 32; fi++) {
        float v = yin[fi];
        #pragma unroll
        for (int g = 0; g < 32; g++) acc[g] = fmaf(v, W1[fi*32 + g], acc[g]);
    }
    #pragma unroll
    for (int g = 0; g < 32; g++)
        acc[g] = acc[g] * __builtin_amdgcn_rcpf(1.0f + __expf(-acc[g]));  // silu
    float out[32];
    #pragma unroll
    for (int g = 0; g < 32; g++) out[g] = (c == 0) ? b2i[g] : 0.0f;
    #pragma unroll
    for (int fi = 0; fi < 32; fi++) {
        float v = acc[fi];
        #pragma unroll
        for (int g = 0; g < 32; g++) out[g] = fmaf(v, W2[fi*32 + g], out[g]);
    }
    #pragma unroll
    for (int k = 0; k < 8; k++)
        *(float4*)(tile + lane * 33 + 4 * k) =
            make_float4(out[4*k+0], out[4*k+1], out[4*k+2], out[4*k+3]);
    __syncthreads();
    #pragma unroll
    for (int k = 0; k < 8; k++) {
        int e  = lane * 4 + k * 256;
        int al = e >> 5, f = e & 31;
        int ag = t * 64 + al;
        if (ag < N) {
            float4 dv = *(const float4*)(tile + al * 33 + f);
            float* xp = x + (size_t)ag * 288 + c * 32 + f;
            float4 xv = *(const float4*)xp;
            *(float4*)xp = make_float4(xv.x + dv.x, xv.y + dv.y,
                                       xv.z + dv.z, xv.w + dv.w);
        }
    }
}

// --- readout (mono, dip) ----------------------------------------------------
__global__ void readout_kernel(const float* __restrict__ x,
        const int* __restrict__ an, const float* __restrict__ posf,
        const float* __restrict__ wc, void* __restrict__ out, int N,
        const int* __restrict__ flag) {
    int n = blockIdx.x * blockDim.x + threadIdx.x;
    if (n >= N) return;
    bool f32 = (*flag) != 0;
    const float* Wt00  = wc + OFF_WT00;
    const float* Wt11  = wc + OFF_WT11;
    const float* Wmono = wc + OFF_WMONO;
    const float* xb = x + (size_t)n * 288;
    float q[4] = {0.f, 0.f, 0.f, 0.f};
    for (int f = 0; f < 32; f++) {
        float xv = xb[f];
        #pragma unroll
        for (int j = 0; j < 4; j++) q[j] = fmaf(xv, Wt00[f*4 + j], q[j]);
    }
    float ebv = wc[OFF_EB + an[n]];
    #pragma unroll
    for (int m = 0; m < 4; m++) {
        float acc = ebv;
        #pragma unroll
        for (int j = 0; j < 4; j++) acc = fmaf(q[j], Wmono[j*4 + m], acc);
        if (f32) ((float*)out)[n*4 + m] = acc;
        else ((__hip_bfloat16*)out)[n*4 + m] = __float2bfloat16(acc);
    }
    #pragma unroll
    for (int c = 0; c < 3; c++) {
        float pc = posf[n*3 + c];
        const float* xc = xb + (1 + c)*32;
        float dq[4] = {0.f, 0.f, 0.f, 0.f};
        for (int f = 0; f < 32; f++) {
            float xv = xc[f];
            #pragma unroll
            for (int m = 0; m < 4; m++) dq[m] = fmaf(xv, Wt11[f*4 + m], dq[m]);
        }
        #pragma unroll
        for (int m = 0; m < 4; m++) {
            float v = dq[m];
            v = v * __builtin_amdgcn_rcpf(1.0f + __expf(-v));   // silu
            v = fminf(fmaxf(v, -0.3f), 0.3f);                   // clip
            v += pc;
            if (f32) ((float*)out)[N*4 + n*12 + c*4 + m] = v;
            else ((__hip_bfloat16*)out)[N*4 + n*12 + c*4 + m] = __float2bfloat16(v);
        }
    }
}

extern "C" void kernel_launch(void* const* d_in, const int* in_sizes, int n_in,
                              void* d_out, int out_size, void* d_ws, size_t ws_size,
                              hipStream_t stream) {
    const int* an    = (const int*)d_in[0];
    const void* pos  = d_in[1];
    const int* dstI  = (const int*)d_in[2];
    const int* srcI  = (const int*)d_in[3];
    const void* embed= d_in[4];
    const void* Wb   = d_in[5];
    const void* W1   = d_in[6];
    const void* b1   = d_in[7];
    const void* W2   = d_in[8];
    const void* b2   = d_in[9];
    const void* Wt00 = d_in[10];
    const void* Wt11 = d_in[11];
    const void* Wmono= d_in[12];
    const void* eb   = d_in[13];
    int N = in_sizes[0];
    int E = in_sizes[2];

    // ws layout: flag,cnt(16B) | x | y | posf | wc | deg,rowstart,cursor | geo | geo2
    int* flag   = (int*)d_ws;
    int* cnt    = flag + 1;
    float* x    = (float*)((char*)d_ws + 16);
    float* y    = x + (size_t)N * 288;
    float* posf = y + (size_t)N * 288;
    float* wc   = posf + (size_t)N * 3;
    int* deg      = (int*)(wc + WC_TOTAL);
    int* rowstart = deg + N;
    int* cursor   = rowstart + N + 1;
    uintptr_t ga = ((uintptr_t)(cursor + N) + 15) & ~(uintptr_t)15;
    float* geo  = (float*)ga;
    float* geo2 = geo + (size_t)E * 32;
    size_t need = (uintptr_t)(geo2 + (size_t)E * 32) - (uintptr_t)d_ws;
    bool use_csr = (ws_size >= need);

    sniff_kernel<<<1, 64, 0, stream>>>(pos, flag, cnt);
    {
        int tot = N * 3 + WC_TOTAL + N;
        convert_kernel<<<(tot + 255)/256, 256, 0, stream>>>(
            pos, Wb, W1, b1, W2, b2, Wt00, Wt11, Wmono, eb, embed,
            posf, wc, deg, N, flag);
    }
    init_xy_kernel<<<(N*288 + 255)/256, 256, 0, stream>>>(an, wc, x, y, N);
    if (use_csr) {
        compact_kernel<<<(E + 255)/256, 256, 0, stream>>>(posf, srcI, dstI,
                                                          geo, cnt, deg, E);
        scan_kernel<<<1, 1024, 0, stream>>>(deg, rowstart, cursor, N);
        scatter_kernel<<<(E + 255)/256, 256, 0, stream>>>(geo, geo2, cursor, cnt, E);
    }

    int ntiles  = (N + 63) / 64;
    int nunits  = ntiles * 9;
    int ablocks = (nunits + 3) / 4;
    for (int i = 0; i < NITER; i++) {
        if (use_csr)
            edge_gather_kernel<<<(N + 7)/8, 256, 0, stream>>>(x, y, geo2, rowstart,
                wc + OFF_WB + (size_t)i*1536, N);
        else
            edge_inline_kernel<<<2048, 256, 0, stream>>>(x, y, posf, srcI, dstI,
                wc + OFF_WB + (size_t)i*1536, E);
        atom_kernel<<<ablocks, 256, 0, stream>>>(x, y,
            wc + OFF_W1 + (size_t)i*3072, wc + OFF_B1 + (size_t)i*32,
            wc + OFF_W2 + (size_t)i*3072, wc + OFF_B2 + (size_t)i*32,
            N, use_csr ? 0 : 1);
    }
    readout_kernel<<<(N + 255)/256, 256, 0, stream>>>(x, an, posf, wc, d_out, N, flag);
}

// Round 9
// 322.545 us; speedup vs baseline: 1.3441x; 1.0914x over previous
//
#include <hip/hip_runtime.h>
#include <hip/hip_bf16.h>

// ---------------------------------------------------------------------------
// MessagePassingModel: N=10000 atoms, E=160000 edges, NC=9 SH channels,
// F=32 features, NB=16 radial basis, NITER=3.
// R8: all top-5 dispatches are harness poison fills (44us, fixed) -> kernels
// all <43us, visibility lost. R9 (traffic+dispatch cuts, no risky rewrites):
//  - direct CSR build: r2-only histogram -> scan -> geom+place at cursor[d]++
//    (removes geo->geo2 copy pass, 7MB + 1 dispatch)
//  - no y zeroing in CSR path (gather fully overwrites y)
//  - atom kernel keeps staged x in registers (epilogue x re-read removed,
//    11.5MB/iter)
//  - setup merged: sniff+deg-zero | convert+init_x+hist | scan | fill_csr
// ---------------------------------------------------------------------------

#define NITER 3

// wcvt (fp32 converted weights) layout offsets, in floats
#define OFF_WB    0        // [NITER][3][16][32] = 4608
#define OFF_W1    4608     // [NITER][3][32][32] = 9216
#define OFF_B1    13824    // [NITER][32] = 96
#define OFF_W2    13920    // 9216
#define OFF_B2    23136    // 96
#define OFF_WT00  23232    // [32][4] = 128
#define OFF_WT11  23360    // 128
#define OFF_WMONO 23488    // [4][4] = 16
#define OFF_EB    23504    // 18
#define OFF_EMB   23522    // [18][32] = 576
#define WC_TOTAL  24098

__device__ __forceinline__ float b2f(const __hip_bfloat16 v) { return __bfloat162float(v); }

// Analytic real-Gaunt coefficients for l<=2:
#define KC0 0.28209479177387814f
#define KG1 0.21850968611841584f
#define KG2 0.12615662610100802f
#define KG3 0.18022375157287861f
#define KG4 0.09011187578643931f
#define KG5 0.15607834722743988f

__device__ __forceinline__ float ldany(const void* p, int i, bool f32) {
    return f32 ? ((const float*)p)[i] : b2f(((const __hip_bfloat16*)p)[i]);
}

// --- K0: sniff input dtype (thread 0) + zero deg array ----------------------
__global__ void sniff_kernel(const void* __restrict__ pos, int* __restrict__ flag,
                             int* __restrict__ deg, int N) {
    int i = blockIdx.x * blockDim.x + threadIdx.x;
    if (i < N) deg[i] = 0;
    if (i == 0) {
        const __hip_bfloat16* p = (const __hip_bfloat16*)pos;
        int isf32 = 0;
        for (int k = 0; k < 64; k++) {
            float v = b2f(p[k]);
            if (!(fabsf(v) < 1.0e6f)) isf32 = 1;   // NaN also trips
        }
        *flag = isf32;
    }
}

// --- K1: convert posf/wc + init x + r2-only dst histogram (range-split) -----
__global__ void setup_kernel(const void* pos, const void* Wb, const void* W1,
        const void* b1, const void* W2, const void* b2, const void* Wt00,
        const void* Wt11, const void* Wmono, const void* eb, const void* emb,
        const int* __restrict__ an,
        const int* __restrict__ srcI, const int* __restrict__ dstI,
        float* __restrict__ posf, float* __restrict__ wc,
        float* __restrict__ x, int* __restrict__ deg,
        int N, int E, const int* __restrict__ flag) {
    int i = blockIdx.x * blockDim.x + threadIdx.x;
    bool f32 = (*flag) != 0;
    int np = N * 3;
    if (i < np) { posf[i] = ldany(pos, i, f32); return; }
    int j = i - np;
    if (j < WC_TOTAL) {
        const void* src; int rel;
        if      (j < OFF_W1)    { src = Wb;    rel = j; }
        else if (j < OFF_B1)    { src = W1;    rel = j - OFF_W1; }
        else if (j < OFF_W2)    { src = b1;    rel = j - OFF_B1; }
        else if (j < OFF_B2)    { src = W2;    rel = j - OFF_W2; }
        else if (j < OFF_WT00)  { src = b2;    rel = j - OFF_B2; }
        else if (j < OFF_WT11)  { src = Wt00;  rel = j - OFF_WT00; }
        else if (j < OFF_WMONO) { src = Wt11;  rel = j - OFF_WT11; }
        else if (j < OFF_EB)    { src = Wmono; rel = j - OFF_WMONO; }
        else if (j < OFF_EMB)   { src = eb;    rel = j - OFF_EB; }
        else                    { src = emb;   rel = j - OFF_EMB; }
        wc[j] = ldany(src, rel, f32);
        return;
    }
    j -= WC_TOTAL;
    if (j < N * 288) {                        // x init
        int n = j / 288, rem = j % 288;
        float val = 0.0f;
        if (rem < 32) val = ldany(emb, an[n] * 32 + rem, f32);
        x[j] = val;
        return;
    }
    j -= N * 288;
    if (j < E) {                              // r2-only histogram (raw pos)
        int s = srcI[j], d = dstI[j];
        float dx = ldany(pos, s*3+0, f32) - ldany(pos, d*3+0, f32);
        float dy = ldany(pos, s*3+1, f32) - ldany(pos, d*3+1, f32);
        float dz = ldany(pos, s*3+2, f32) - ldany(pos, d*3+2, f32);
        float r2 = dx*dx + dy*dy + dz*dz + 1e-12f;
        if (r2 < 16.0f) atomicAdd(&deg[d], 1);
    }
}

// --- K2: single-block exclusive scan of deg -> rowstart, cursor -------------
__global__ __launch_bounds__(1024) void scan_kernel(const int* __restrict__ deg,
        int* __restrict__ rowstart, int* __restrict__ cursor, int N) {
    __shared__ int part[1024];
    int tid = threadIdx.x;
    int chunk = (N + 1023) / 1024;
    int beg = tid * chunk;
    int sum = 0;
    for (int k = 0; k < chunk; k++) {
        int i = beg + k;
        if (i < N) sum += deg[i];
    }
    part[tid] = sum;
    __syncthreads();
    for (int off = 1; off < 1024; off <<= 1) {
        int v = (tid >= off) ? part[tid - off] : 0;
        __syncthreads();
        part[tid] += v;
        __syncthreads();
    }
    int run = (tid == 0) ? 0 : part[tid - 1];
    for (int k = 0; k < chunk; k++) {
        int i = beg + k;
        if (i < N) { rowstart[i] = run; cursor[i] = run; run += deg[i]; }
    }
    if (tid == 1023) rowstart[N] = run;
}

// --- geometry helper --------------------------------------------------------
__device__ __forceinline__ bool edge_geom(float dx, float dy, float dz,
                                          float* sp, float* rad) {
    float r2 = dx*dx + dy*dy + dz*dz + 1e-12f;
    if (r2 >= 16.0f) return false;
    float r  = sqrtf(r2);
    float t2 = r2 * 0.0625f;
    float fc = __expf(-t2 / (1.0f - t2));
    float u = 1.0f / (1.0f + r);
    float v = 1.0f - u;
    const float BIN[16] = {1.f,15.f,105.f,455.f,1365.f,3003.f,5005.f,6435.f,
                           6435.f,5005.f,3003.f,1365.f,455.f,105.f,15.f,1.f};
    float vp[16];
    vp[0] = 1.0f;
    #pragma unroll
    for (int k = 1; k < 16; k++) vp[k] = vp[k-1] * v;
    float up = 1.0f;
    #pragma unroll
    for (int n = 0; n < 16; n++) { rad[n] = BIN[n] * up * vp[15-n] * fc; up *= u; }
    float ir = 1.0f / r;
    float ux = dx*ir, uy = dy*ir, uz = dz*ir;
    const float c0 = 0.28209479177387814f, c1 = 0.4886025119029199f;
    const float c2a = 1.0925484305920792f, c2b = 0.31539156525252005f, c2c = 0.5462742152960396f;
    sp[0] = c0;
    sp[1] = c1*uy; sp[2] = c1*uz; sp[3] = c1*ux;
    sp[4] = c2a*ux*uy; sp[5] = c2a*uy*uz; sp[6] = c2b*(3.0f*uz*uz - 1.0f);
    sp[7] = c2a*ux*uz; sp[8] = c2c*(ux*ux - uy*uy);
    return true;
}

// --- K3: fill CSR directly (geom + place at cursor[d]++) --------------------
__global__ void fill_csr_kernel(const float* __restrict__ posf,
        const int* __restrict__ srcI, const int* __restrict__ dstI,
        float* __restrict__ geo2, int* __restrict__ cursor, int E) {
    int e = blockIdx.x * blockDim.x + threadIdx.x;
    if (e >= E) return;
    int s = srcI[e], d = dstI[e];
    float sp[9], rad[16];
    if (!edge_geom(posf[s*3+0] - posf[d*3+0],
                   posf[s*3+1] - posf[d*3+1],
                   posf[s*3+2] - posf[d*3+2], sp, rad)) return;
    int slot = atomicAdd(&cursor[d], 1);
    float* gp = geo2 + (size_t)slot * 32;
    gp[0] = __int_as_float(s);
    gp[1] = 0.0f;
    #pragma unroll
    for (int a = 0; a < 9; a++) gp[2 + a] = sp[a];
    gp[11] = 0.0f;
    #pragma unroll
    for (int k = 0; k < 16; k++) gp[16 + k] = rad[k];
}

// --- per-iteration: dst-gather message accumulation (NO atomics) ------------
__global__ __launch_bounds__(256) void edge_gather_kernel(
        const float* __restrict__ x, float* __restrict__ y,
        const float* __restrict__ geo2, const int* __restrict__ rowstart,
        const float* __restrict__ Wbi, int N) {
    int f = threadIdx.x & 31;
    int n = (blockIdx.x * blockDim.x + threadIdx.x) >> 5;   // dst atom
    if (n >= N) return;
    float w0[16], w1[16], w2[16];
    #pragma unroll
    for (int k = 0; k < 16; k++) {
        w0[k] = Wbi[(0*16 + k)*32 + f];
        w1[k] = Wbi[(1*16 + k)*32 + f];
        w2[k] = Wbi[(2*16 + k)*32 + f];
    }
    float A0=0.f,A1=0.f,A2=0.f,A3=0.f,A4=0.f,A5=0.f,A6=0.f,A7=0.f,A8=0.f;
    int beg = rowstart[n], end = rowstart[n+1];
    for (int e = beg; e < end; e++) {
        const float4* gp = (const float4*)(geo2 + (size_t)e * 32);
        float4 h0 = gp[0], h1 = gp[1], h2 = gp[2];
        float4 r0 = gp[4], r1 = gp[5], r2 = gp[6], r3 = gp[7];
        int s = __float_as_int(h0.x);
        float rad[16] = {r0.x,r0.y,r0.z,r0.w, r1.x,r1.y,r1.z,r1.w,
                         r2.x,r2.y,r2.z,r2.w, r3.x,r3.y,r3.z,r3.w};
        float rw0 = 0.f, rw1 = 0.f, rw2 = 0.f;
        #pragma unroll
        for (int k = 0; k < 16; k++) {
            rw0 = fmaf(rad[k], w0[k], rw0);
            rw1 = fmaf(rad[k], w1[k], rw1);
            rw2 = fmaf(rad[k], w2[k], rw2);
        }
        float B0 = h0.z*rw0;
        float B1 = h0.w*rw1, B2 = h1.x*rw1, B3 = h1.y*rw1;
        float B4 = h1.z*rw2, B5 = h1.w*rw2, B6 = h2.x*rw2,
              B7 = h2.y*rw2, B8 = h2.z*rw2;
        const float* xp = x + (size_t)s*288 + f;
        float X0 = xp[0],   X1 = xp[32],  X2 = xp[64],  X3 = xp[96],  X4 = xp[128];
        float X5 = xp[160], X6 = xp[192], X7 = xp[224], X8 = xp[256];
        A0 += KC0*(X0*B0 + X1*B1 + X2*B2 + X3*B3 + X4*B4 + X5*B5 + X6*B6 + X7*B7 + X8*B8);
        A1 += KC0*(X0*B1 + X1*B0) + KG1*(X3*B4 + X4*B3 + X2*B5 + X5*B2)
            - KG2*(X1*B6 + X6*B1) - KG1*(X1*B8 + X8*B1);
        A2 += KC0*(X0*B2 + X2*B0) + KG1*(X1*B5 + X5*B1 + X3*B7 + X7*B3)
            + 2.0f*KG2*(X2*B6 + X6*B2);
        A3 += KC0*(X0*B3 + X3*B0) + KG1*(X1*B4 + X4*B1 + X2*B7 + X7*B2)
            - KG2*(X3*B6 + X6*B3) + KG1*(X3*B8 + X8*B3);
        A4 += KC0*(X0*B4 + X4*B0) + KG1*(X1*B3 + X3*B1) + KG5*(X5*B7 + X7*B5)
            - KG3*(X4*B6 + X6*B4);
        A5 += KC0*(X0*B5 + X5*B0) + KG1*(X1*B2 + X2*B1) + KG5*(X4*B7 + X7*B4)
            + KG4*(X5*B6 + X6*B5) - KG5*(X5*B8 + X8*B5);
        A6 += KC0*(X0*B6 + X6*B0) - KG2*X1*B1 + 2.0f*KG2*X2*B2 - KG2*X3*B3
            - KG3*X4*B4 + KG4*X5*B5 + KG3*X6*B6 + KG4*X7*B7 - KG3*X8*B8;
        A7 += KC0*(X0*B7 + X7*B0) + KG1*(X2*B3 + X3*B2) + KG5*(X4*B5 + X5*B4)
            + KG4*(X6*B7 + X7*B6) + KG5*(X7*B8 + X8*B7);
        A8 += KC0*(X0*B8 + X8*B0) - KG1*X1*B1 + KG1*X3*B3 - KG5*X5*B5 + KG5*X7*B7
            - KG3*(X6*B8 + X8*B6);
    }
    float* yp = y + (size_t)n * 288 + f;
    yp[0]   = A0; yp[32]  = A1; yp[64]  = A2; yp[96]  = A3; yp[128] = A4;
    yp[160] = A5; yp[192] = A6; yp[224] = A7; yp[256] = A8;
}

// --- atom update: x += dense2(silu(dense1(x + ymsg))) -----------------------
// R7 lane-owns-atom GEMV via LDS pitch-33 transpose; staged x float4s are
// RETAINED in registers for the epilogue (no x re-read).
__global__ __launch_bounds__(256) void atom_kernel(
        float* __restrict__ x, const float* __restrict__ y,
        const float* __restrict__ W1i, const float* __restrict__ b1i,
        const float* __restrict__ W2i, const float* __restrict__ b2i,
        int N) {
    __shared__ float sm[4][64*33];
    int lane  = threadIdx.x & 63;
    int wslot = threadIdx.x >> 6;
    int u = __builtin_amdgcn_readfirstlane(blockIdx.x * 4 + wslot);
    int t = u / 9;
    int c = u - t * 9;                      // channel (uniform)
    int d = (c == 0) ? 0 : ((c < 4) ? 1 : 2);
    const float* W1 = W1i + d * 1024;
    const float* W2 = W2i + d * 1024;
    float* tile = sm[wslot];
    float4 xr4[8];
    #pragma unroll
    for (int k = 0; k < 8; k++) {
        int e  = lane * 4 + k * 256;
        int al = e >> 5, f = e & 31;
        int ag = t * 64 + al;
        float4 s = make_float4(0.f, 0.f, 0.f, 0.f);
        float4 xv = make_float4(0.f, 0.f, 0.f, 0.f);
        if (ag < N) {
            xv = *(const float4*)(x + (size_t)ag * 288 + c * 32 + f);
            float4 yv = *(const float4*)(y + (size_t)ag * 288 + c * 32 + f);
            s = make_float4(xv.x + yv.x, xv.y + yv.y, xv.z + yv.z, xv.w + yv.w);
        }
        xr4[k] = xv;
        *(float4*)(tile + al * 33 + f) = s;
    }
    __syncthreads();
    float yin[32];
    #pragma unroll
    for (int k = 0; k < 8; k++) {
        float4 v = *(const float4*)(tile + lane * 33 + 4 * k);
        yin[4*k+0] = v.x; yin[4*k+1] = v.y; yin[4*k+2] = v.z; yin[4*k+3] = v.w;
    }
    float acc[32];
    #pragma unroll
    for (int g = 0; g < 32; g++) acc[g] = (c == 0) ? b1i[g] : 0.0f;
    #pragma unroll
    for (int fi = 0; fi < 32; fi++) {
        float v = yin[fi];
        #pragma unroll
        for (int g = 0; g < 32; g++) acc[g] = fmaf(v, W1[fi*32 + g], acc[g]);
    }
    #pragma unroll
    for (int g = 0; g < 32; g++)
        acc[g] = acc[g] * __builtin_amdgcn_rcpf(1.0f + __expf(-acc[g]));  // silu
    float out[32];
    #pragma unroll
    for (int g = 0; g < 32; g++) out[g] = (c == 0) ? b2i[g] : 0.0f;
    #pragma unroll
    for (int fi = 0; fi < 32; fi++) {
        float v = acc[fi];
        #pragma unroll
        for (int g = 0; g < 32; g++) out[g] = fmaf(v, W2[fi*32 + g], out[g]);
    }
    __syncthreads();   // tile reuse barrier
    #pragma unroll
    for (int k = 0; k < 8; k++)
        *(float4*)(tile + lane * 33 + 4 * k) =
            make_float4(out[4*k+0], out[4*k+1], out[4*k+2], out[4*k+3]);
    __syncthreads();
    #pragma unroll
    for (int k = 0; k < 8; k++) {
        int e  = lane * 4 + k * 256;
        int al = e >> 5, f = e & 31;
        int ag = t * 64 + al;
        if (ag < N) {
            float4 dv = *(const float4*)(tile + al * 33 + f);
            float4 xv = xr4[k];
            *(float4*)(x + (size_t)ag * 288 + c * 32 + f) =
                make_float4(xv.x + dv.x, xv.y + dv.y, xv.z + dv.z, xv.w + dv.w);
        }
    }
}

// --- fallback (no-CSR): inline-geometry edge kernel with atomics ------------
__global__ void zero_kernel(float4* __restrict__ b, int n) {
    int i = blockIdx.x * blockDim.x + threadIdx.x;
    int stride = gridDim.x * blockDim.x;
    float4 z = make_float4(0.f, 0.f, 0.f, 0.f);
    for (; i < n; i += stride) b[i] = z;
}

__global__ __launch_bounds__(256) void edge_inline_kernel(
        const float* __restrict__ x, float* __restrict__ y,
        const float* __restrict__ posf,
        const int* __restrict__ srcI, const int* __restrict__ dstI,
        const float* __restrict__ Wbi, int E) {
    int f  = threadIdx.x & 31;
    int hw = (blockIdx.x * blockDim.x + threadIdx.x) >> 5;
    int nhw = gridDim.x * (blockDim.x >> 5);
    float w0[16], w1[16], w2[16];
    #pragma unroll
    for (int n = 0; n < 16; n++) {
        w0[n] = Wbi[(0*16 + n)*32 + f];
        w1[n] = Wbi[(1*16 + n)*32 + f];
        w2[n] = Wbi[(2*16 + n)*32 + f];
    }
    for (int e = hw; e < E; e += nhw) {
        int s = srcI[e], d = dstI[e];
        float sp[9], rad[16];
        if (!edge_geom(posf[s*3+0] - posf[d*3+0],
                       posf[s*3+1] - posf[d*3+1],
                       posf[s*3+2] - posf[d*3+2], sp, rad)) continue;
        float rw0 = 0.f, rw1 = 0.f, rw2 = 0.f;
        #pragma unroll
        for (int n = 0; n < 16; n++) {
            rw0 = fmaf(rad[n], w0[n], rw0);
            rw1 = fmaf(rad[n], w1[n], rw1);
            rw2 = fmaf(rad[n], w2[n], rw2);
        }
        float B0 = sp[0]*rw0;
        float B1 = sp[1]*rw1, B2 = sp[2]*rw1, B3 = sp[3]*rw1;
        float B4 = sp[4]*rw2, B5 = sp[5]*rw2, B6 = sp[6]*rw2,
              B7 = sp[7]*rw2, B8 = sp[8]*rw2;
        const float* xp = x + (size_t)s*288 + f;
        float X0 = xp[0],   X1 = xp[32],  X2 = xp[64],  X3 = xp[96],  X4 = xp[128];
        float X5 = xp[160], X6 = xp[192], X7 = xp[224], X8 = xp[256];
        float* yp = y + (size_t)d*288 + f;
        float m;
        m = KC0*(X0*B0 + X1*B1 + X2*B2 + X3*B3 + X4*B4 + X5*B5 + X6*B6 + X7*B7 + X8*B8);
        unsafeAtomicAdd(yp + 0, m);
        m = KC0*(X0*B1 + X1*B0) + KG1*(X3*B4 + X4*B3 + X2*B5 + X5*B2)
          - KG2*(X1*B6 + X6*B1) - KG1*(X1*B8 + X8*B1);
        unsafeAtomicAdd(yp + 32, m);
        m = KC0*(X0*B2 + X2*B0) + KG1*(X1*B5 + X5*B1 + X3*B7 + X7*B3)
          + 2.0f*KG2*(X2*B6 + X6*B2);
        unsafeAtomicAdd(yp + 64, m);
        m = KC0*(X0*B3 + X3*B0) + KG1*(X1*B4 + X4*B1 + X2*B7 + X7*B2)
          - KG2*(X3*B6 + X6*B3) + KG1*(X3*B8 + X8*B3);
        unsafeAtomicAdd(yp + 96, m);
        m = KC0*(X0*B4 + X4*B0) + KG1*(X1*B3 + X3*B1) + KG5*(X5*B7 + X7*B5)
          - KG3*(X4*B6 + X6*B4);
        unsafeAtomicAdd(yp + 128, m);
        m = KC0*(X0*B5 + X5*B0) + KG1*(X1*B2 + X2*B1) + KG5*(X4*B7 + X7*B4)
          + KG4*(X5*B6 + X6*B5) - KG5*(X5*B8 + X8*B5);
        unsafeAtomicAdd(yp + 160, m);
        m = KC0*(X0*B6 + X6*B0) - KG2*X1*B1 + 2.0f*KG2*X2*B2 - KG2*X3*B3
          - KG3*X4*B4 + KG4*X5*B5 + KG3*X6*B6 + KG4*X7*B7 - KG3*X8*B8;
        unsafeAtomicAdd(yp + 192, m);
        m = KC0*(X0*B7 + X7*B0) + KG1*(X2*B3 + X3*B2) + KG5*(X4*B5 + X5*B4)
          + KG4*(X6*B7 + X7*B6) + KG5*(X7*B8 + X8*B7);
        unsafeAtomicAdd(yp + 224, m);
        m = KC0*(X0*B8 + X8*B0) - KG1*X1*B1 + KG1*X3*B3 - KG5*X5*B5 + KG5*X7*B7
          - KG3*(X6*B8 + X8*B6);
        unsafeAtomicAdd(yp + 256, m);
    }
}

// --- readout (mono, dip) ----------------------------------------------------
__global__ void readout_kernel(const float* __restrict__ x,
        const int* __restrict__ an, const float* __restrict__ posf,
        const float* __restrict__ wc, void* __restrict__ out, int N,
        const int* __restrict__ flag) {
    int n = blockIdx.x * blockDim.x + threadIdx.x;
    if (n >= N) return;
    bool f32 = (*flag) != 0;
    const float* Wt00  = wc + OFF_WT00;
    const float* Wt11  = wc + OFF_WT11;
    const float* Wmono = wc + OFF_WMONO;
    const float* xb = x + (size_t)n * 288;
    float q[4] = {0.f, 0.f, 0.f, 0.f};
    for (int f = 0; f < 32; f++) {
        float xv = xb[f];
        #pragma unroll
        for (int j = 0; j < 4; j++) q[j] = fmaf(xv, Wt00[f*4 + j], q[j]);
    }
    float ebv = wc[OFF_EB + an[n]];
    #pragma unroll
    for (int m = 0; m < 4; m++) {
        float acc = ebv;
        #pragma unroll
        for (int j = 0; j < 4; j++) acc = fmaf(q[j], Wmono[j*4 + m], acc);
        if (f32) ((float*)out)[n*4 + m] = acc;
        else ((__hip_bfloat16*)out)[n*4 + m] = __float2bfloat16(acc);
    }
    #pragma unroll
    for (int c = 0; c < 3; c++) {
        float pc = posf[n*3 + c];
        const float* xc = xb + (1 + c)*32;
        float dq[4] = {0.f, 0.f, 0.f, 0.f};
        for (int f = 0; f < 32; f++) {
            float xv = xc[f];
            #pragma unroll
            for (int m = 0; m < 4; m++) dq[m] = fmaf(xv, Wt11[f*4 + m], dq[m]);
        }
        #pragma unroll
        for (int m = 0; m < 4; m++) {
            float v = dq[m];
            v = v * __builtin_amdgcn_rcpf(1.0f + __expf(-v));   // silu
            v = fminf(fmaxf(v, -0.3f), 0.3f);                   // clip
            v += pc;
            if (f32) ((float*)out)[N*4 + n*12 + c*4 + m] = v;
            else ((__hip_bfloat16*)out)[N*4 + n*12 + c*4 + m] = __float2bfloat16(v);
        }
    }
}

extern "C" void kernel_launch(void* const* d_in, const int* in_sizes, int n_in,
                              void* d_out, int out_size, void* d_ws, size_t ws_size,
                              hipStream_t stream) {
    const int* an    = (const int*)d_in[0];
    const void* pos  = d_in[1];
    const int* dstI  = (const int*)d_in[2];
    const int* srcI  = (const int*)d_in[3];
    const void* embed= d_in[4];
    const void* Wb   = d_in[5];
    const void* W1   = d_in[6];
    const void* b1   = d_in[7];
    const void* W2   = d_in[8];
    const void* b2   = d_in[9];
    const void* Wt00 = d_in[10];
    const void* Wt11 = d_in[11];
    const void* Wmono= d_in[12];
    const void* eb   = d_in[13];
    int N = in_sizes[0];
    int E = in_sizes[2];

    // ws layout: flag(16B) | x | y | posf | wc | deg,rowstart,cursor | geo2
    int* flag   = (int*)d_ws;
    float* x    = (float*)((char*)d_ws + 16);
    float* y    = x + (size_t)N * 288;
    float* posf = y + (size_t)N * 288;
    float* wc   = posf + (size_t)N * 3;
    int* deg      = (int*)(wc + WC_TOTAL);
    int* rowstart = deg + N;
    int* cursor   = rowstart + N + 1;
    uintptr_t ga = ((uintptr_t)(cursor + N) + 15) & ~(uintptr_t)15;
    float* geo2 = (float*)ga;
    size_t need = (uintptr_t)(geo2 + (size_t)E * 32) - (uintptr_t)d_ws;
    bool use_csr = (ws_size >= need);

    sniff_kernel<<<(N + 255)/256, 256, 0, stream>>>(pos, flag, deg, N);
    {
        int tot = N * 3 + WC_TOTAL + N * 288 + E;
        setup_kernel<<<(tot + 255)/256, 256, 0, stream>>>(
            pos, Wb, W1, b1, W2, b2, Wt00, Wt11, Wmono, eb, embed,
            an, srcI, dstI, posf, wc, x, deg, N, E, flag);
    }
    if (use_csr) {
        scan_kernel<<<1, 1024, 0, stream>>>(deg, rowstart, cursor, N);
        fill_csr_kernel<<<(E + 255)/256, 256, 0, stream>>>(posf, srcI, dstI,
                                                           geo2, cursor, E);
    }

    int ntiles  = (N + 63) / 64;
    int nunits  = ntiles * 9;
    int ablocks = (nunits + 3) / 4;
    for (int i = 0; i < NITER; i++) {
        if (use_csr) {
            edge_gather_kernel<<<(N + 7)/8, 256, 0, stream>>>(x, y, geo2, rowstart,
                wc + OFF_WB + (size_t)i*1536, N);
        } else {
            zero_kernel<<<512, 256, 0, stream>>>((float4*)y, N * 72);
            edge_inline_kernel<<<2048, 256, 0, stream>>>(x, y, posf, srcI, dstI,
                wc + OFF_WB + (size_t)i*1536, E);
        }
        atom_kernel<<<ablocks, 256, 0, stream>>>(x, y,
            wc + OFF_W1 + (size_t)i*3072, wc + OFF_B1 + (size_t)i*32,
            wc + OFF_W2 + (size_t)i*3072, wc + OFF_B2 + (size_t)i*32, N);
    }
    readout_kernel<<<(N + 255)/256, 256, 0, stream>>>(x, an, posf, wc, d_out, N, flag);
}